// Round 7
// baseline (266.659 us; speedup 1.0000x reference)
//
#include <hip/hip_runtime.h>
#include <stdint.h>

#define SEQ 4096
#define EMB 768
#define HEADS 12
#define HD 64

typedef __attribute__((ext_vector_type(8))) short short8;
typedef __attribute__((ext_vector_type(4))) short short4v;
typedef __attribute__((ext_vector_type(8))) __bf16 bf16x8;
typedef __attribute__((ext_vector_type(4))) __bf16 bf16x4;
typedef __attribute__((ext_vector_type(4))) float f32x4;

// scale * log2(e) folded into Q: (1/sqrt(64)) * 1.4426950408889634
#define QSCALE 0.18033688011112043f

static __device__ __forceinline__ unsigned short f2bf(float f) {
    unsigned int u = __builtin_bit_cast(unsigned int, f);
    unsigned int r = 0x7fffu + ((u >> 16) & 1u);
    u += r;
    return (unsigned short)(u >> 16);
}

static __device__ __forceinline__ f32x4 mfma32(short8 a, short8 b, f32x4 c) {
    return __builtin_amdgcn_mfma_f32_16x16x32_bf16(
        __builtin_bit_cast(bf16x8, a), __builtin_bit_cast(bf16x8, b), c, 0, 0, 0);
}

static __device__ __forceinline__ f32x4 mfma16(short4v a, short4v b, f32x4 c) {
#if __has_builtin(__builtin_amdgcn_mfma_f32_16x16x16_bf16)
    return __builtin_amdgcn_mfma_f32_16x16x16_bf16(
        __builtin_bit_cast(bf16x4, a), __builtin_bit_cast(bf16x4, b), c, 0, 0, 0);
#else
    return __builtin_amdgcn_mfma_f32_16x16x16bf16_1k(a, b, c, 0, 0, 0);
#endif
}

static __device__ __forceinline__ short4v pack4bf(float a, float b, float c, float d) {
#if __has_builtin(__builtin_amdgcn_cvt_pk_bf16_f32)
    typedef __attribute__((ext_vector_type(2))) __bf16 bf16x2;
    bf16x2 lo = __builtin_amdgcn_cvt_pk_bf16_f32(a, b);
    bf16x2 hi = __builtin_amdgcn_cvt_pk_bf16_f32(c, d);
    uint2 u = {__builtin_bit_cast(unsigned int, lo), __builtin_bit_cast(unsigned int, hi)};
    return __builtin_bit_cast(short4v, u);
#else
    short4v p;
    p[0] = (short)f2bf(a); p[1] = (short)f2bf(b);
    p[2] = (short)f2bf(c); p[3] = (short)f2bf(d);
    return p;
#endif
}

static __device__ __forceinline__ void load_lds16(const void* g, void* l) {
    __builtin_amdgcn_global_load_lds(
        (const __attribute__((address_space(1))) unsigned int*)(uintptr_t)g,
        (__attribute__((address_space(3))) unsigned int*)(uintptr_t)l, 16, 0, 0);
}

// coarse partial-id for (h, i128, ch>=1); 36 slots/head, 432 total
static __device__ __forceinline__ int pid_coarse(int h, int i128, int ch) {
    int b = (i128 < 20) ? (i128 - 10)
                        : (i128 < 30 ? 10 + (i128 - 20) * 2 : 30 + (i128 - 30) * 3);
    return h * 36 + b + (ch - 1);
}

// fine partial-id for (h, i128, ch>=1); nch = 2/4/6/8 -> 1/3/5/7 partials per
// i128; 104 slots/head, 1248 total
static __device__ __forceinline__ int pid_fine(int h, int i128, int ch) {
    int b = (i128 < 10) ? i128
          : (i128 < 20) ? 10 + (i128 - 10) * 3
          : (i128 < 30) ? 40 + (i128 - 20) * 5
                        : 90 + (i128 - 30) * 7;
    return h * 104 + b + (ch - 1);
}

// online-softmax step over one 64-k tile held as st[4] (S^T layout).
// Common path is LANE-LOCAL only (15-op fmax tree, no cross-lane). The
// cross-quad shfl reduce + rescale live inside the rare defer-max branch.
// m_i stays quad-uniform by induction, so P fed to the k-spanning PV MFMA is
// consistently normalized.
static __device__ __forceinline__ void softmax_q(f32x4* st, float& m_i, float& l_i,
                                                 f32x4* O, short4v* pk) {
    float t0 = fmaxf(fmaxf(st[0][0], st[0][1]), fmaxf(st[0][2], st[0][3]));
    float t1 = fmaxf(fmaxf(st[1][0], st[1][1]), fmaxf(st[1][2], st[1][3]));
    float t2 = fmaxf(fmaxf(st[2][0], st[2][1]), fmaxf(st[2][2], st[2][3]));
    float t3 = fmaxf(fmaxf(st[3][0], st[3][1]), fmaxf(st[3][2], st[3][3]));
    float mx = fmaxf(fmaxf(t0, t1), fmaxf(t2, t3));  // this lane's 16 values
    if (__ballot(mx > m_i + 5.0f)) {  // rare after warm-up
        mx = fmaxf(mx, __shfl_xor(mx, 16));
        mx = fmaxf(mx, __shfl_xor(mx, 32));  // per-q (cross-quad) max
        const bool inc = mx > m_i;
        const float mn = inc ? mx : m_i;
        const float alpha = __builtin_amdgcn_exp2f(m_i - mn);
        m_i = mn;
        l_i *= alpha;
        for (int dt = 0; dt < 4; dt++)
            for (int r = 0; r < 4; r++) O[dt][r] *= alpha;
    }
    float rs = 0.f;
    for (int nt = 0; nt < 4; nt++) {
        float p0 = __builtin_amdgcn_exp2f(st[nt][0] - m_i);
        float p1 = __builtin_amdgcn_exp2f(st[nt][1] - m_i);
        float p2 = __builtin_amdgcn_exp2f(st[nt][2] - m_i);
        float p3 = __builtin_amdgcn_exp2f(st[nt][3] - m_i);
        rs += p0 + p1 + p2 + p3;
        pk[nt] = pack4bf(p0, p1, p2, p3);
    }
    l_i += rs;  // per-lane partial; reduced across quads at epilogue
}

// ---------------------------------------------------------------- fused convert
__global__ __launch_bounds__(256) void convert_all(const float* __restrict__ x,
                                                   const float* __restrict__ wq,
                                                   const float* __restrict__ wk,
                                                   const float* __restrict__ wv,
                                                   const float* __restrict__ wo,
                                                   unsigned short* __restrict__ xb,
                                                   unsigned short* __restrict__ wqkvT,
                                                   unsigned short* __restrict__ woT) {
    __shared__ float Ls[64][65];
    const int bid = blockIdx.x;
    if (bid < 3072) {
        int i = bid * 256 + threadIdx.x;
        float4 v = ((const float4*)x)[i];
        ushort4 o = {f2bf(v.x), f2bf(v.y), f2bf(v.z), f2bf(v.w)};
        ((ushort4*)xb)[i] = o;
        return;
    }
    const int idx = bid - 3072;
    const int z = idx / 144;
    const int bx = (idx % 144) / 12, by = idx % 12;
    const float* W = (z == 0) ? wq : (z == 1) ? wk : (z == 2) ? wv : wo;
    unsigned short* dst = (z < 3) ? (wqkvT + (size_t)z * EMB * EMB) : woT;
    const int k0 = bx * 64, n0 = by * 64;
    const int r = threadIdx.x >> 2, c0 = (threadIdx.x & 3) * 16;
    for (int j = 0; j < 16; j += 4) {
        float4 v = *(const float4*)&W[(size_t)(k0 + r) * EMB + n0 + c0 + j];
        Ls[r][c0 + j] = v.x;
        Ls[r][c0 + j + 1] = v.y;
        Ls[r][c0 + j + 2] = v.z;
        Ls[r][c0 + j + 3] = v.w;
    }
    __syncthreads();
    unsigned short tmp[16];
    for (int j = 0; j < 16; j++) tmp[j] = f2bf(Ls[c0 + j][r]);
    *(uint4*)&dst[(size_t)(n0 + r) * EMB + k0 + c0] = *(uint4*)tmp;
    *(uint4*)&dst[(size_t)(n0 + r) * EMB + k0 + c0 + 8] = *(uint4*)(tmp + 8);
}

// ---------------------------------------------------------------- 128x128 QKV GEMM
__global__ __launch_bounds__(256) void gemm_qkv(const unsigned short* __restrict__ A,
                                                const unsigned short* __restrict__ Bt,
                                                const float* __restrict__ b0p,
                                                const float* __restrict__ b1p,
                                                const float* __restrict__ b2p,
                                                unsigned short* __restrict__ QKb,
                                                unsigned short* __restrict__ Vtb) {
    __shared__ __align__(16) unsigned short SMEM[16384];  // [buf*8192]: As 4096 | Bs 4096
    const int tid = threadIdx.x;
    const int wave = tid >> 6, lane = tid & 63, quad = lane >> 4, l16 = lane & 15;
    const int m0 = blockIdx.x * 128, n0 = blockIdx.y * 128;
    const int wm = (wave >> 1) * 64, wn = (wave & 1) * 64;
    const int lrow = lane >> 2, lcol = (lane & 3) * 8;

    f32x4 acc[4][4] = {};

    for (int t = 0; t < 2; t++) {
        int row = wave * 32 + t * 16 + lrow;
        load_lds16(&A[(size_t)(m0 + row) * EMB + lcol], &SMEM[(wave * 2 + t) * 512]);
        load_lds16(&Bt[(size_t)(n0 + row) * EMB + lcol], &SMEM[4096 + (wave * 2 + t) * 512]);
    }
    int buf = 0;
    for (int k0 = 0; k0 < EMB; k0 += 32) {
        __syncthreads();  // drains this buf's DMA; other buf free
        if (k0 + 32 < EMB) {
            unsigned short* A_ = &SMEM[(buf ^ 1) * 8192];
            unsigned short* B_ = A_ + 4096;
            for (int t = 0; t < 2; t++) {
                int row = wave * 32 + t * 16 + lrow;
                load_lds16(&A[(size_t)(m0 + row) * EMB + k0 + 32 + lcol], &A_[(wave * 2 + t) * 512]);
                load_lds16(&Bt[(size_t)(n0 + row) * EMB + k0 + 32 + lcol], &B_[(wave * 2 + t) * 512]);
            }
        }
        const unsigned short* A_ = &SMEM[buf * 8192];
        const unsigned short* B_ = A_ + 4096;
        short8 a[4], b[4];
        for (int i = 0; i < 4; i++) a[i] = *(const short8*)&A_[(wm + i * 16 + l16) * 32 + quad * 8];
        for (int i = 0; i < 4; i++) b[i] = *(const short8*)&B_[(wn + i * 16 + l16) * 32 + quad * 8];
        for (int i = 0; i < 4; i++)
            for (int j = 0; j < 4; j++) acc[i][j] = mfma32(a[i], b[j], acc[i][j]);
        buf ^= 1;
    }

    const int z = n0 / EMB;  // block-uniform: 0=Q, 1=K, 2=V
    if (z < 2) {
        const float* bias = z ? b1p : b0p;
        const float sc = z ? 1.0f : QSCALE;
        for (int i = 0; i < 4; i++)
            for (int j = 0; j < 4; j++) {
                int mbase = m0 + wm + i * 16 + quad * 4;
                int n = n0 + wn + j * 16 + l16;  // 0..1535 natural col
                float bv = bias[n - z * EMB];
                for (int r = 0; r < 4; r++)
                    QKb[(size_t)(mbase + r) * 1536 + n] = f2bf((acc[i][j][r] + bv) * sc);
            }
    } else {
        const int nn = n0 + wn + l16 - 2 * EMB;
        for (int j = 0; j < 4; j++) {
            __syncthreads();
            const float bv = b2p[nn + j * 16];
            const int nloc = (wave & 1) * 16 + l16;
            for (int i = 0; i < 4; i++) {
                ushort4 pk;
                pk.x = f2bf(acc[i][j][0] + bv);
                pk.y = f2bf(acc[i][j][1] + bv);
                pk.z = f2bf(acc[i][j][2] + bv);
                pk.w = f2bf(acc[i][j][3] + bv);
                *(ushort4*)&SMEM[nloc * 136 + wm + i * 16 + quad * 4] = pk;
            }
            __syncthreads();
            const int nl = tid >> 3, c = tid & 7;
            const int ng = (nl >> 4) * 64 + j * 16 + (nl & 15) + n0 - 2 * EMB;
            const int hh = ng >> 6, dd = ng & 63;
            unsigned short* dst = &Vtb[(size_t)(hh * HD + dd) * SEQ + m0];
            *(uint4*)&dst[c * 8] = *(uint4*)&SMEM[nl * 136 + c * 8];
            *(uint4*)&dst[64 + c * 8] = *(uint4*)&SMEM[nl * 136 + 64 + c * 8];
        }
    }
}

// ---------------------------------------------------------------- 64x128 out-proj GEMM
__global__ __launch_bounds__(256) void gemm_out(const unsigned short* __restrict__ A,
                                                const unsigned short* __restrict__ Bt,
                                                const float* __restrict__ bias,
                                                float* __restrict__ outp) {
    __shared__ __align__(16) unsigned short SMEM[12288];  // As[2]@0/2048, Bs[2]@4096/8192
    const int tid = threadIdx.x;
    const int wave = tid >> 6, lane = tid & 63, quad = lane >> 4, l16 = lane & 15;
    const int m0 = blockIdx.x * 64, n0 = blockIdx.y * 128;
    const int wm = (wave >> 1) * 32, wn = (wave & 1) * 64;
    const int lrow = lane >> 2, lcol = (lane & 3) * 8;

    f32x4 acc[2][4] = {};

    load_lds16(&A[(size_t)(m0 + wave * 16 + lrow) * EMB + lcol], &SMEM[wave * 512]);
    for (int t = 0; t < 2; t++) {
        int row = wave * 32 + t * 16 + lrow;
        load_lds16(&Bt[(size_t)(n0 + row) * EMB + lcol], &SMEM[4096 + (wave * 2 + t) * 512]);
    }
    int buf = 0;
    for (int k0 = 0; k0 < EMB; k0 += 32) {
        __syncthreads();
        if (k0 + 32 < EMB) {
            unsigned short* A_ = &SMEM[(buf ^ 1) * 2048];
            unsigned short* B_ = &SMEM[4096 + (buf ^ 1) * 4096];
            load_lds16(&A[(size_t)(m0 + wave * 16 + lrow) * EMB + k0 + 32 + lcol], &A_[wave * 512]);
            for (int t = 0; t < 2; t++) {
                int row = wave * 32 + t * 16 + lrow;
                load_lds16(&Bt[(size_t)(n0 + row) * EMB + k0 + 32 + lcol], &B_[(wave * 2 + t) * 512]);
            }
        }
        const unsigned short* A_ = &SMEM[buf * 2048];
        const unsigned short* B_ = &SMEM[4096 + buf * 4096];
        short8 a[2], b[4];
        for (int i = 0; i < 2; i++) a[i] = *(const short8*)&A_[(wm + i * 16 + l16) * 32 + quad * 8];
        for (int j = 0; j < 4; j++) b[j] = *(const short8*)&B_[(wn + j * 16 + l16) * 32 + quad * 8];
        for (int i = 0; i < 2; i++)
            for (int j = 0; j < 4; j++) acc[i][j] = mfma32(a[i], b[j], acc[i][j]);
        buf ^= 1;
    }

    for (int i = 0; i < 2; i++)
        for (int j = 0; j < 4; j++) {
            int mbase = m0 + wm + i * 16 + quad * 4;
            int n = n0 + wn + j * 16 + l16;
            float bv = bias[n];
            for (int r = 0; r < 4; r++) outp[(size_t)(mbase + r) * EMB + n] = acc[i][j][r] + bv;
        }
}

// ---------------------------------------------------------------- attention
// R17: 16 KB LDS (Ks + Vs SINGLE-buffered, 8 KB each) to double HW residency.
// Evidence: occupancy tracked LDS size exactly (24-32 KB -> ~2 blocks/CU =
// 21-23%; R15's 16 KB -> 34% = supply-limited) -> effective LDS occupancy
// window ~64 KB. R15's slowdown was register SPILL (extra k0/k1 arrays), not
// the 16 KB config; this kernel keeps R13's exact register state (84 VGPR).
// Iteration order makes single-buffering safe:
//   SM(t) -> PV(t) -> barrier -> stage(t+1 from regs, issue loads t+2)
//   -> barrier -> QK(t+1)
// (2 barriers/tile, same as R13; QK(t) is always consumed before Ks is
// overwritten, PV(t) before Vs is overwritten.) Fine grid (12x136 = 1632
// blocks, 6.4 blocks/CU supply >= 4 cap); launch_bounds(256,4) caps VGPR at
// 128. No setprio (R16: neutral-to-negative).
template <bool FINE>
__global__ __launch_bounds__(256, 4) void attn_kernel(const unsigned short* __restrict__ QKb,
                                                      const unsigned short* __restrict__ Vtb,
                                                      unsigned short* __restrict__ ctxb,
                                                      unsigned short* __restrict__ Op,
                                                      float* __restrict__ mArr,
                                                      float* __restrict__ lArr) {
    __shared__ __align__(16) unsigned short Ks[64 * 64];  // 8 KB
    __shared__ __align__(16) unsigned short Vs[64 * 64];  // 8 KB

    const int bid = blockIdx.x;
    const int h = bid % HEADS;
    int i128, ch, nch;
    if (FINE) {
        const int r2 = 135 - bid / HEADS;  // big i128 (long chunks) first
        if (r2 < 20) {
            i128 = r2 >> 1; ch = r2 & 1; nch = 2;
        } else if (r2 < 60) {
            int t = r2 - 20; i128 = 10 + (t >> 2); ch = t & 3; nch = 4;
        } else if (r2 < 120) {
            int t = r2 - 60; i128 = 20 + t / 6; ch = t % 6; nch = 6;
        } else {
            int t = r2 - 120; i128 = 30 + (t >> 3); ch = t & 7; nch = 8;
        }
    } else {
        const int r2 = 67 - bid / HEADS;  // big i128 (long chunks) first
        if (r2 < 10) {
            i128 = r2; ch = 0; nch = 1;
        } else if (r2 < 30) {
            int t = r2 - 10; i128 = 10 + (t >> 1); ch = t & 1; nch = 2;
        } else if (r2 < 60) {
            int t = r2 - 30; i128 = 20 + t / 3; ch = t % 3; nch = 3;
        } else {
            int t = r2 - 60; i128 = 30 + (t >> 2); ch = t & 3; nch = 4;
        }
    }
    const int T = 2 * i128 + 2;
    const int kb = ch * T / nch;
    const int ke = (ch + 1) * T / nch - 1;
    const int qbase = i128 * 128;
    const int tid = threadIdx.x;
    const int wave = tid >> 6, lane = tid & 63, quad = lane >> 4, l16 = lane & 15;

    const unsigned short* Qg = QKb + (size_t)h * HD;          // row stride 1536
    const unsigned short* Kg = QKb + (size_t)(EMB + h * HD);  // row stride 1536
    const unsigned short* Vh = Vtb + (size_t)h * HD * SEQ;    // [d][m]

    const int qa = qbase + wave * 32 + l16;  // set a: waves 0..3 cover 128 q-rows
    const int qb = qa + 16;                  // set b
    const short8 bQ0a = *(const short8*)&Qg[(size_t)qa * 1536 + quad * 8];
    const short8 bQ1a = *(const short8*)&Qg[(size_t)qa * 1536 + 32 + quad * 8];
    const short8 bQ0b = *(const short8*)&Qg[(size_t)qb * 1536 + quad * 8];
    const short8 bQ1b = *(const short8*)&Qg[(size_t)qb * 1536 + 32 + quad * 8];

    const int row = tid >> 2, t4 = tid & 3;  // 256 threads: 64 rows x 4 chunks
    const int swk = row & 7, swv = row & 15;

    f32x4 Oa[4] = {}, Ob[4] = {};
    float m_a = -3.0e38f, l_a = 0.f;
    float m_b = -3.0e38f, l_b = 0.f;

    uint4 kr0, kr1, vr0, vr1;
    {
        const int kb64 = kb * 64;
        const unsigned short* kp = &Kg[(size_t)(kb64 + row) * 1536];
        kr0 = *(const uint4*)&kp[(2 * t4) * 8];
        kr1 = *(const uint4*)&kp[(2 * t4 + 1) * 8];
        const unsigned short* vp = &Vh[(size_t)row * SEQ + kb64];
        vr0 = *(const uint4*)&vp[t4 * 16];
        vr1 = *(const uint4*)&vp[t4 * 16 + 8];
    }
    // tile kb -> Ks + Vs
    *(uint4*)&Ks[row * 64 + ((2 * t4) ^ swk) * 8] = kr0;
    *(uint4*)&Ks[row * 64 + ((2 * t4 + 1) ^ swk) * 8] = kr1;
    *(uint2*)&Vs[row * 64 + ((4 * t4) ^ swv) * 4] = ((const uint2*)&vr0)[0];
    *(uint2*)&Vs[row * 64 + ((4 * t4 + 1) ^ swv) * 4] = ((const uint2*)&vr0)[1];
    *(uint2*)&Vs[row * 64 + ((4 * t4 + 2) ^ swv) * 4] = ((const uint2*)&vr1)[0];
    *(uint2*)&Vs[row * 64 + ((4 * t4 + 3) ^ swv) * 4] = ((const uint2*)&vr1)[1];
    if (kb < ke) {
        const int nb = (kb + 1) * 64;
        const unsigned short* kp = &Kg[(size_t)(nb + row) * 1536];
        kr0 = *(const uint4*)&kp[(2 * t4) * 8];
        kr1 = *(const uint4*)&kp[(2 * t4 + 1) * 8];
        const unsigned short* vp = &Vh[(size_t)row * SEQ + nb];
        vr0 = *(const uint4*)&vp[t4 * 16];
        vr1 = *(const uint4*)&vp[t4 * 16 + 8];
    }
    __syncthreads();

    const int qw = qbase + wave * 32 + 31;  // wave's last causal q-row
    const int swr = l16 & 7;

    // prologue QK(kb) -> sa/sb (pipeline priming)
    f32x4 sa[4], sb[4];
    if (kb * 64 <= qw) {
        for (int nt = 0; nt < 4; nt++) {
            short8 aK0 = *(const short8*)&Ks[(nt * 16 + l16) * 64 + (quad ^ swr) * 8];
            short8 aK1 = *(const short8*)&Ks[(nt * 16 + l16) * 64 + ((quad + 4) ^ swr) * 8];
            f32x4 za = {};
            za = mfma32(aK0, bQ0a, za);
            za = mfma32(aK1, bQ1a, za);
            sa[nt] = za;
            f32x4 zb = {};
            zb = mfma32(aK0, bQ0b, zb);
            zb = mfma32(aK1, bQ1b, zb);
            sb[nt] = zb;
        }
        if (kb * 64 + 63 > qbase + wave * 32) {
            for (int nt = 0; nt < 4; nt++)
                for (int r = 0; r < 4; r++) {
                    const int kk = kb * 64 + nt * 16 + quad * 4 + r;
                    if (kk > qa) sa[nt][r] = -INFINITY;
                    if (kk > qb) sb[nt][r] = -INFINITY;
                }
        }
    }

    for (int kt = kb; kt <= ke; kt++) {
        const int kbase = kt * 64;
        const bool cur = (kbase <= qw);

        // SM(kt) then PV(kt): both consume tile-kt state before any overwrite
        if (cur) {
            short4v pka[4], pkb[4];
            softmax_q(sa, m_a, l_a, Oa, pka);
            softmax_q(sb, m_b, l_b, Ob, pkb);
            for (int dt = 0; dt < 4; dt++)
                for (int nt = 0; nt < 4; nt++) {
                    short4v av =
                        *(const short4v*)&Vs[(dt * 16 + l16) * 64 + ((4 * nt + quad) ^ l16) * 4];
                    Oa[dt] = mfma16(av, pka[nt], Oa[dt]);
                    Ob[dt] = mfma16(av, pkb[nt], Ob[dt]);
                }
        }

        __syncthreads();  // all waves done reading Ks(kt)/Vs(kt)
        if (kt < ke) {
            // stage tile kt+1 from regs; then issue loads for kt+2
            *(uint4*)&Ks[row * 64 + ((2 * t4) ^ swk) * 8] = kr0;
            *(uint4*)&Ks[row * 64 + ((2 * t4 + 1) ^ swk) * 8] = kr1;
            *(uint2*)&Vs[row * 64 + ((4 * t4) ^ swv) * 4] = ((const uint2*)&vr0)[0];
            *(uint2*)&Vs[row * 64 + ((4 * t4 + 1) ^ swv) * 4] = ((const uint2*)&vr0)[1];
            *(uint2*)&Vs[row * 64 + ((4 * t4 + 2) ^ swv) * 4] = ((const uint2*)&vr1)[0];
            *(uint2*)&Vs[row * 64 + ((4 * t4 + 3) ^ swv) * 4] = ((const uint2*)&vr1)[1];
            if (kt + 1 < ke) {
                const int nb = (kt + 2) * 64;
                const unsigned short* kp = &Kg[(size_t)(nb + row) * 1536];
                kr0 = *(const uint4*)&kp[(2 * t4) * 8];
                kr1 = *(const uint4*)&kp[(2 * t4 + 1) * 8];
                const unsigned short* vp = &Vh[(size_t)row * SEQ + nb];
                vr0 = *(const uint4*)&vp[t4 * 16];
                vr1 = *(const uint4*)&vp[t4 * 16 + 8];
            }
        }
        __syncthreads();  // tile kt+1 staged & visible

        // QK(kt+1): MFMA from freshly staged Ks; overlaps the kt+2 load latency
        const int kn = kbase + 64;
        if (kt < ke && kn <= qw) {
            for (int nt = 0; nt < 4; nt++) {
                short8 aK0 = *(const short8*)&Ks[(nt * 16 + l16) * 64 + (quad ^ swr) * 8];
                short8 aK1 = *(const short8*)&Ks[(nt * 16 + l16) * 64 + ((quad + 4) ^ swr) * 8];
                f32x4 za = {};
                za = mfma32(aK0, bQ0a, za);
                za = mfma32(aK1, bQ1a, za);
                sa[nt] = za;
                f32x4 zb = {};
                zb = mfma32(aK0, bQ0b, zb);
                zb = mfma32(aK1, bQ1b, zb);
                sb[nt] = zb;
            }
            if (kn + 63 > qbase + wave * 32) {
                for (int nt = 0; nt < 4; nt++)
                    for (int r = 0; r < 4; r++) {
                        const int kk = kn + nt * 16 + quad * 4 + r;
                        if (kk > qa) sa[nt][r] = -INFINITY;
                        if (kk > qb) sb[nt][r] = -INFINITY;
                    }
            }
        }
    }

    // deferred cross-lane l reduction (m is quad-uniform by construction)
    l_a += __shfl_xor(l_a, 16);
    l_a += __shfl_xor(l_a, 32);
    l_b += __shfl_xor(l_b, 16);
    l_b += __shfl_xor(l_b, 32);

    const int qla = wave * 32 + l16;  // 0..127 across 4 waves (set a)
    const int qlb = qla + 16;         // set b
    if (!FINE && nch == 1) {
        const float ia = 1.f / l_a, ib = 1.f / l_b;
        for (int dt = 0; dt < 4; dt++) {
            ushort4 oa, ob;
            oa.x = f2bf(Oa[dt][0] * ia);
            oa.y = f2bf(Oa[dt][1] * ia);
            oa.z = f2bf(Oa[dt][2] * ia);
            oa.w = f2bf(Oa[dt][3] * ia);
            ob.x = f2bf(Ob[dt][0] * ib);
            ob.y = f2bf(Ob[dt][1] * ib);
            ob.z = f2bf(Ob[dt][2] * ib);
            ob.w = f2bf(Ob[dt][3] * ib);
            *(ushort4*)&ctxb[(size_t)qa * EMB + h * HD + dt * 16 + quad * 4] = oa;
            *(ushort4*)&ctxb[(size_t)qb * EMB + h * HD + dt * 16 + quad * 4] = ob;
        }
    } else {
        if (ch == 0) {
            for (int dt = 0; dt < 4; dt++) {
                ushort4 oa, ob;
                oa.x = f2bf(Oa[dt][0]);
                oa.y = f2bf(Oa[dt][1]);
                oa.z = f2bf(Oa[dt][2]);
                oa.w = f2bf(Oa[dt][3]);
                ob.x = f2bf(Ob[dt][0]);
                ob.y = f2bf(Ob[dt][1]);
                ob.z = f2bf(Ob[dt][2]);
                ob.w = f2bf(Ob[dt][3]);
                *(ushort4*)&ctxb[(size_t)qa * EMB + h * HD + dt * 16 + quad * 4] = oa;
                *(ushort4*)&ctxb[(size_t)qb * EMB + h * HD + dt * 16 + quad * 4] = ob;
            }
        } else {
            const int pid = FINE ? pid_fine(h, i128, ch) : pid_coarse(h, i128, ch);
            for (int dt = 0; dt < 4; dt++) {
                ushort4 oa, ob;
                oa.x = f2bf(Oa[dt][0]);
                oa.y = f2bf(Oa[dt][1]);
                oa.z = f2bf(Oa[dt][2]);
                oa.w = f2bf(Oa[dt][3]);
                ob.x = f2bf(Ob[dt][0]);
                ob.y = f2bf(Ob[dt][1]);
                ob.z = f2bf(Ob[dt][2]);
                ob.w = f2bf(Ob[dt][3]);
                *(ushort4*)&Op[(size_t)pid * 8192 + qla * 64 + dt * 16 + quad * 4] = oa;
                *(ushort4*)&Op[(size_t)pid * 8192 + qlb * 64 + dt * 16 + quad * 4] = ob;
            }
        }
        if (quad == 0) {
            const int MLS = FINE ? 8 : 4;
            const int mlb = ((h * 32 + i128) * MLS + ch) * 128;
            mArr[mlb + qla] = m_a;
            lArr[mlb + qla] = l_a;
            mArr[mlb + qlb] = m_b;
            lArr[mlb + qlb] = l_b;
        }
    }
}

// ---------------------------------------------------------------- merge
// coarse: 264 blocks, i128 10..31, nch 2/3/4. fine: 384 blocks, i128 0..31,
// nch 2/4/6/8.
template <bool FINE>
__global__ __launch_bounds__(256) void merge_kernel(const unsigned short* __restrict__ Op,
                                                    const float* __restrict__ mArr,
                                                    const float* __restrict__ lArr,
                                                    unsigned short* __restrict__ ctxb) {
    const int gid = blockIdx.x;
    const int h = gid % HEADS;
    const int i128 = FINE ? (gid / HEADS) : (10 + gid / HEADS);
    int nch;
    if (FINE)
        nch = (i128 < 10) ? 2 : (i128 < 20) ? 4 : (i128 < 30) ? 6 : 8;
    else
        nch = (i128 < 20) ? 2 : (i128 < 30) ? 3 : 4;
    const int MLS = FINE ? 8 : 4;
    const int q = threadIdx.x >> 1, d0 = (threadIdx.x & 1) * 32;
    const int mlbase = (h * 32 + i128) * MLS;

    float mc[8], lc[8];
    for (int c = 0; c < nch; c++) {
        mc[c] = mArr[(mlbase + c) * 128 + q];
        lc[c] = lArr[(mlbase + c) * 128 + q];
    }
    float M = mc[0];
    for (int c = 1; c < nch; c++) M = fmaxf(M, mc[c]);
    float w[8], L = 0.f;
    for (int c = 0; c < nch; c++) {
        w[c] = __builtin_amdgcn_exp2f(mc[c] - M);
        L += w[c] * lc[c];
    }
    const float inv = 1.f / L;
    for (int c = 0; c < nch; c++) w[c] *= inv;

    unsigned short* dst = &ctxb[(size_t)(i128 * 128 + q) * EMB + h * HD + d0];
    for (int jj = 0; jj < 32; jj += 8) {
        uint4 u0 = *(const uint4*)&dst[jj];  // chunk0 (unnormalized) in place
        float f[8];
        const unsigned short* p0 = (const unsigned short*)&u0;
        for (int t = 0; t < 8; t++)
            f[t] = w[0] * __builtin_bit_cast(float, (unsigned int)p0[t] << 16);
        for (int c = 1; c < nch; c++) {
            const int pid = FINE ? pid_fine(h, i128, c) : pid_coarse(h, i128, c);
            uint4 u = *(const uint4*)&Op[(size_t)pid * 8192 + q * 64 + d0 + jj];
            const unsigned short* p = (const unsigned short*)&u;
            for (int t = 0; t < 8; t++)
                f[t] += w[c] * __builtin_bit_cast(float, (unsigned int)p[t] << 16);
        }
        unsigned short o[8];
        for (int t = 0; t < 8; t++) o[t] = f2bf(f[t]);
        *(uint4*)&dst[jj] = *(uint4*)o;
    }
}

// ---------------------------------------------------------------- launch
extern "C" void kernel_launch(void* const* d_in, const int* in_sizes, int n_in,
                              void* d_out, int out_size, void* d_ws, size_t ws_size,
                              hipStream_t stream) {
    const float* x = (const float*)d_in[0];
    const float* wq = (const float*)d_in[1];
    const float* bq = (const float*)d_in[2];
    const float* wk = (const float*)d_in[3];
    const float* bk = (const float*)d_in[4];
    const float* wv = (const float*)d_in[5];
    const float* bv = (const float*)d_in[6];
    const float* wo = (const float*)d_in[7];
    const float* bo = (const float*)d_in[8];

    unsigned short* ws = (unsigned short*)d_ws;
    unsigned short* xb = ws;                          // 3,145,728 ush
    unsigned short* wqkvT = xb + SEQ * EMB;           // 1,769,472
    unsigned short* woT = wqkvT + 3 * EMB * EMB;      // 589,824
    unsigned short* QKb = woT + EMB * EMB;            // 4096*1536 -> ends 11,796,480
    unsigned short* Vtb = QKb + (size_t)SEQ * 1536;   // 3,145,728 -> ends 14,942,208
    unsigned short* ctxb = Vtb + HEADS * SEQ * HD;    // 3,145,728 -> ends 18,087,936

    convert_all<<<dim3(3072 + 576), 256, 0, stream>>>(x, wq, wk, wv, wo, xb, wqkvT, woT);
    gemm_qkv<<<dim3(SEQ / 128, 3 * EMB / 128), 256, 0, stream>>>(
        xb, wqkvT, bq, bk, bv, QKb, Vtb);

    // fine layout lives past the base workspace end (ctxb end = 18,087,936 ush):
    //   OpF   1248 * 8192            = 10,223,616 ush -> ends 28,311,552
    //   mArrF 393,216 f32            =    786,432 ush -> ends 29,097,984
    //   lArrF 393,216 f32            =    786,432 ush -> ends 29,884,416  (59.77 MB)
    const bool fine = ws_size >= (size_t)29884416 * 2;
    if (fine) {
        unsigned short* OpF = ws + 18087936u;
        float* mF = (float*)(ws + 28311552u);
        float* lF = mF + 393216;
        attn_kernel<true><<<dim3(12 * 136), 256, 0, stream>>>(QKb, Vtb, ctxb, OpF, mF, lF);
        merge_kernel<true><<<dim3(12 * 32), 256, 0, stream>>>(OpF, mF, lF, ctxb);
    } else {
        // coarse scratch aliases xb+wqkvT (dead after gemm_qkv):
        // Op 432*8192 = 3,538,944 ush; mArr/lArr 196,608 f32 each
        unsigned short* Op = xb;
        float* mArr = (float*)(ws + 3538944);
        float* lArr = mArr + 196608;
        attn_kernel<false><<<dim3(12 * 68), 256, 0, stream>>>(QKb, Vtb, ctxb, Op, mArr, lArr);
        merge_kernel<false><<<dim3(264), 256, 0, stream>>>(Op, mArr, lArr, ctxb);
    }
    gemm_out<<<dim3(SEQ / 64, EMB / 128), 256, 0, stream>>>(ctxb, woT, bo, (float*)d_out);
}

// Round 8
// 192.545 us; speedup vs baseline: 1.3849x; 1.3849x over previous
//
#include <hip/hip_runtime.h>
#include <stdint.h>

#define SEQ 4096
#define EMB 768
#define HEADS 12
#define HD 64

typedef __attribute__((ext_vector_type(8))) short short8;
typedef __attribute__((ext_vector_type(4))) short short4v;
typedef __attribute__((ext_vector_type(8))) __bf16 bf16x8;
typedef __attribute__((ext_vector_type(4))) __bf16 bf16x4;
typedef __attribute__((ext_vector_type(4))) float f32x4;

// scale * log2(e) folded into Q: (1/sqrt(64)) * 1.4426950408889634
#define QSCALE 0.18033688011112043f

static __device__ __forceinline__ unsigned short f2bf(float f) {
    unsigned int u = __builtin_bit_cast(unsigned int, f);
    unsigned int r = 0x7fffu + ((u >> 16) & 1u);
    u += r;
    return (unsigned short)(u >> 16);
}

static __device__ __forceinline__ f32x4 mfma32(short8 a, short8 b, f32x4 c) {
    return __builtin_amdgcn_mfma_f32_16x16x32_bf16(
        __builtin_bit_cast(bf16x8, a), __builtin_bit_cast(bf16x8, b), c, 0, 0, 0);
}

static __device__ __forceinline__ f32x4 mfma16(short4v a, short4v b, f32x4 c) {
#if __has_builtin(__builtin_amdgcn_mfma_f32_16x16x16_bf16)
    return __builtin_amdgcn_mfma_f32_16x16x16_bf16(
        __builtin_bit_cast(bf16x4, a), __builtin_bit_cast(bf16x4, b), c, 0, 0, 0);
#else
    return __builtin_amdgcn_mfma_f32_16x16x16bf16_1k(a, b, c, 0, 0, 0);
#endif
}

static __device__ __forceinline__ short4v pack4bf(float a, float b, float c, float d) {
#if __has_builtin(__builtin_amdgcn_cvt_pk_bf16_f32)
    typedef __attribute__((ext_vector_type(2))) __bf16 bf16x2;
    bf16x2 lo = __builtin_amdgcn_cvt_pk_bf16_f32(a, b);
    bf16x2 hi = __builtin_amdgcn_cvt_pk_bf16_f32(c, d);
    uint2 u = {__builtin_bit_cast(unsigned int, lo), __builtin_bit_cast(unsigned int, hi)};
    return __builtin_bit_cast(short4v, u);
#else
    short4v p;
    p[0] = (short)f2bf(a); p[1] = (short)f2bf(b);
    p[2] = (short)f2bf(c); p[3] = (short)f2bf(d);
    return p;
#endif
}

static __device__ __forceinline__ void load_lds16(const void* g, void* l) {
    __builtin_amdgcn_global_load_lds(
        (const __attribute__((address_space(1))) unsigned int*)(uintptr_t)g,
        (__attribute__((address_space(3))) unsigned int*)(uintptr_t)l, 16, 0, 0);
}

// coarse partial-id for (h, i128, ch>=1); 36 slots/head, 432 total
static __device__ __forceinline__ int pid_coarse(int h, int i128, int ch) {
    int b = (i128 < 20) ? (i128 - 10)
                        : (i128 < 30 ? 10 + (i128 - 20) * 2 : 30 + (i128 - 30) * 3);
    return h * 36 + b + (ch - 1);
}

// fine partial-id for (h, i128, ch>=1); nch = 2/4/6/8 -> 1/3/5/7 partials per
// i128; 104 slots/head, 1248 total
static __device__ __forceinline__ int pid_fine(int h, int i128, int ch) {
    int b = (i128 < 10) ? i128
          : (i128 < 20) ? 10 + (i128 - 10) * 3
          : (i128 < 30) ? 40 + (i128 - 20) * 5
                        : 90 + (i128 - 30) * 7;
    return h * 104 + b + (ch - 1);
}

// online-softmax step over one 64-k tile held as st[4] (S^T layout).
// Common path is LANE-LOCAL only (15-op fmax tree, no cross-lane). The
// cross-quad shfl reduce + rescale live inside the rare defer-max branch.
// m_i stays quad-uniform by induction, so P fed to the k-spanning PV MFMA is
// consistently normalized.
static __device__ __forceinline__ void softmax_q(f32x4* st, float& m_i, float& l_i,
                                                 f32x4* O, short4v* pk) {
    float t0 = fmaxf(fmaxf(st[0][0], st[0][1]), fmaxf(st[0][2], st[0][3]));
    float t1 = fmaxf(fmaxf(st[1][0], st[1][1]), fmaxf(st[1][2], st[1][3]));
    float t2 = fmaxf(fmaxf(st[2][0], st[2][1]), fmaxf(st[2][2], st[2][3]));
    float t3 = fmaxf(fmaxf(st[3][0], st[3][1]), fmaxf(st[3][2], st[3][3]));
    float mx = fmaxf(fmaxf(t0, t1), fmaxf(t2, t3));  // this lane's 16 values
    if (__ballot(mx > m_i + 5.0f)) {  // rare after warm-up
        mx = fmaxf(mx, __shfl_xor(mx, 16));
        mx = fmaxf(mx, __shfl_xor(mx, 32));  // per-q (cross-quad) max
        const bool inc = mx > m_i;
        const float mn = inc ? mx : m_i;
        const float alpha = __builtin_amdgcn_exp2f(m_i - mn);
        m_i = mn;
        l_i *= alpha;
        for (int dt = 0; dt < 4; dt++)
            for (int r = 0; r < 4; r++) O[dt][r] *= alpha;
    }
    float rs = 0.f;
    for (int nt = 0; nt < 4; nt++) {
        float p0 = __builtin_amdgcn_exp2f(st[nt][0] - m_i);
        float p1 = __builtin_amdgcn_exp2f(st[nt][1] - m_i);
        float p2 = __builtin_amdgcn_exp2f(st[nt][2] - m_i);
        float p3 = __builtin_amdgcn_exp2f(st[nt][3] - m_i);
        rs += p0 + p1 + p2 + p3;
        pk[nt] = pack4bf(p0, p1, p2, p3);
    }
    l_i += rs;  // per-lane partial; reduced across quads at epilogue
}

// ---------------------------------------------------------------- fused convert
__global__ __launch_bounds__(256) void convert_all(const float* __restrict__ x,
                                                   const float* __restrict__ wq,
                                                   const float* __restrict__ wk,
                                                   const float* __restrict__ wv,
                                                   const float* __restrict__ wo,
                                                   unsigned short* __restrict__ xb,
                                                   unsigned short* __restrict__ wqkvT,
                                                   unsigned short* __restrict__ woT) {
    __shared__ float Ls[64][65];
    const int bid = blockIdx.x;
    if (bid < 3072) {
        int i = bid * 256 + threadIdx.x;
        float4 v = ((const float4*)x)[i];
        ushort4 o = {f2bf(v.x), f2bf(v.y), f2bf(v.z), f2bf(v.w)};
        ((ushort4*)xb)[i] = o;
        return;
    }
    const int idx = bid - 3072;
    const int z = idx / 144;
    const int bx = (idx % 144) / 12, by = idx % 12;
    const float* W = (z == 0) ? wq : (z == 1) ? wk : (z == 2) ? wv : wo;
    unsigned short* dst = (z < 3) ? (wqkvT + (size_t)z * EMB * EMB) : woT;
    const int k0 = bx * 64, n0 = by * 64;
    const int r = threadIdx.x >> 2, c0 = (threadIdx.x & 3) * 16;
    for (int j = 0; j < 16; j += 4) {
        float4 v = *(const float4*)&W[(size_t)(k0 + r) * EMB + n0 + c0 + j];
        Ls[r][c0 + j] = v.x;
        Ls[r][c0 + j + 1] = v.y;
        Ls[r][c0 + j + 2] = v.z;
        Ls[r][c0 + j + 3] = v.w;
    }
    __syncthreads();
    unsigned short tmp[16];
    for (int j = 0; j < 16; j++) tmp[j] = f2bf(Ls[c0 + j][r]);
    *(uint4*)&dst[(size_t)(n0 + r) * EMB + k0 + c0] = *(uint4*)tmp;
    *(uint4*)&dst[(size_t)(n0 + r) * EMB + k0 + c0 + 8] = *(uint4*)(tmp + 8);
}

// ---------------------------------------------------------------- 128x128 QKV GEMM
__global__ __launch_bounds__(256) void gemm_qkv(const unsigned short* __restrict__ A,
                                                const unsigned short* __restrict__ Bt,
                                                const float* __restrict__ b0p,
                                                const float* __restrict__ b1p,
                                                const float* __restrict__ b2p,
                                                unsigned short* __restrict__ QKb,
                                                unsigned short* __restrict__ Vtb) {
    __shared__ __align__(16) unsigned short SMEM[16384];  // [buf*8192]: As 4096 | Bs 4096
    const int tid = threadIdx.x;
    const int wave = tid >> 6, lane = tid & 63, quad = lane >> 4, l16 = lane & 15;
    const int m0 = blockIdx.x * 128, n0 = blockIdx.y * 128;
    const int wm = (wave >> 1) * 64, wn = (wave & 1) * 64;
    const int lrow = lane >> 2, lcol = (lane & 3) * 8;

    f32x4 acc[4][4] = {};

    for (int t = 0; t < 2; t++) {
        int row = wave * 32 + t * 16 + lrow;
        load_lds16(&A[(size_t)(m0 + row) * EMB + lcol], &SMEM[(wave * 2 + t) * 512]);
        load_lds16(&Bt[(size_t)(n0 + row) * EMB + lcol], &SMEM[4096 + (wave * 2 + t) * 512]);
    }
    int buf = 0;
    for (int k0 = 0; k0 < EMB; k0 += 32) {
        __syncthreads();  // drains this buf's DMA; other buf free
        if (k0 + 32 < EMB) {
            unsigned short* A_ = &SMEM[(buf ^ 1) * 8192];
            unsigned short* B_ = A_ + 4096;
            for (int t = 0; t < 2; t++) {
                int row = wave * 32 + t * 16 + lrow;
                load_lds16(&A[(size_t)(m0 + row) * EMB + k0 + 32 + lcol], &A_[(wave * 2 + t) * 512]);
                load_lds16(&Bt[(size_t)(n0 + row) * EMB + k0 + 32 + lcol], &B_[(wave * 2 + t) * 512]);
            }
        }
        const unsigned short* A_ = &SMEM[buf * 8192];
        const unsigned short* B_ = A_ + 4096;
        short8 a[4], b[4];
        for (int i = 0; i < 4; i++) a[i] = *(const short8*)&A_[(wm + i * 16 + l16) * 32 + quad * 8];
        for (int i = 0; i < 4; i++) b[i] = *(const short8*)&B_[(wn + i * 16 + l16) * 32 + quad * 8];
        for (int i = 0; i < 4; i++)
            for (int j = 0; j < 4; j++) acc[i][j] = mfma32(a[i], b[j], acc[i][j]);
        buf ^= 1;
    }

    const int z = n0 / EMB;  // block-uniform: 0=Q, 1=K, 2=V
    if (z < 2) {
        const float* bias = z ? b1p : b0p;
        const float sc = z ? 1.0f : QSCALE;
        for (int i = 0; i < 4; i++)
            for (int j = 0; j < 4; j++) {
                int mbase = m0 + wm + i * 16 + quad * 4;
                int n = n0 + wn + j * 16 + l16;  // 0..1535 natural col
                float bv = bias[n - z * EMB];
                for (int r = 0; r < 4; r++)
                    QKb[(size_t)(mbase + r) * 1536 + n] = f2bf((acc[i][j][r] + bv) * sc);
            }
    } else {
        const int nn = n0 + wn + l16 - 2 * EMB;
        for (int j = 0; j < 4; j++) {
            __syncthreads();
            const float bv = b2p[nn + j * 16];
            const int nloc = (wave & 1) * 16 + l16;
            for (int i = 0; i < 4; i++) {
                ushort4 pk;
                pk.x = f2bf(acc[i][j][0] + bv);
                pk.y = f2bf(acc[i][j][1] + bv);
                pk.z = f2bf(acc[i][j][2] + bv);
                pk.w = f2bf(acc[i][j][3] + bv);
                *(ushort4*)&SMEM[nloc * 136 + wm + i * 16 + quad * 4] = pk;
            }
            __syncthreads();
            const int nl = tid >> 3, c = tid & 7;
            const int ng = (nl >> 4) * 64 + j * 16 + (nl & 15) + n0 - 2 * EMB;
            const int hh = ng >> 6, dd = ng & 63;
            unsigned short* dst = &Vtb[(size_t)(hh * HD + dd) * SEQ + m0];
            *(uint4*)&dst[c * 8] = *(uint4*)&SMEM[nl * 136 + c * 8];
            *(uint4*)&dst[64 + c * 8] = *(uint4*)&SMEM[nl * 136 + 64 + c * 8];
        }
    }
}

// ---------------------------------------------------------------- 64x128 out-proj GEMM
__global__ __launch_bounds__(256) void gemm_out(const unsigned short* __restrict__ A,
                                                const unsigned short* __restrict__ Bt,
                                                const float* __restrict__ bias,
                                                float* __restrict__ outp) {
    __shared__ __align__(16) unsigned short SMEM[12288];  // As[2]@0/2048, Bs[2]@4096/8192
    const int tid = threadIdx.x;
    const int wave = tid >> 6, lane = tid & 63, quad = lane >> 4, l16 = lane & 15;
    const int m0 = blockIdx.x * 64, n0 = blockIdx.y * 128;
    const int wm = (wave >> 1) * 32, wn = (wave & 1) * 64;
    const int lrow = lane >> 2, lcol = (lane & 3) * 8;

    f32x4 acc[2][4] = {};

    load_lds16(&A[(size_t)(m0 + wave * 16 + lrow) * EMB + lcol], &SMEM[wave * 512]);
    for (int t = 0; t < 2; t++) {
        int row = wave * 32 + t * 16 + lrow;
        load_lds16(&Bt[(size_t)(n0 + row) * EMB + lcol], &SMEM[4096 + (wave * 2 + t) * 512]);
    }
    int buf = 0;
    for (int k0 = 0; k0 < EMB; k0 += 32) {
        __syncthreads();
        if (k0 + 32 < EMB) {
            unsigned short* A_ = &SMEM[(buf ^ 1) * 2048];
            unsigned short* B_ = &SMEM[4096 + (buf ^ 1) * 4096];
            load_lds16(&A[(size_t)(m0 + wave * 16 + lrow) * EMB + k0 + 32 + lcol], &A_[wave * 512]);
            for (int t = 0; t < 2; t++) {
                int row = wave * 32 + t * 16 + lrow;
                load_lds16(&Bt[(size_t)(n0 + row) * EMB + k0 + 32 + lcol], &B_[(wave * 2 + t) * 512]);
            }
        }
        const unsigned short* A_ = &SMEM[buf * 2048];
        const unsigned short* B_ = &SMEM[4096 + buf * 4096];
        short8 a[2], b[4];
        for (int i = 0; i < 2; i++) a[i] = *(const short8*)&A_[(wm + i * 16 + l16) * 32 + quad * 8];
        for (int j = 0; j < 4; j++) b[j] = *(const short8*)&B_[(wn + j * 16 + l16) * 32 + quad * 8];
        for (int i = 0; i < 2; i++)
            for (int j = 0; j < 4; j++) acc[i][j] = mfma32(a[i], b[j], acc[i][j]);
        buf ^= 1;
    }

    for (int i = 0; i < 2; i++)
        for (int j = 0; j < 4; j++) {
            int mbase = m0 + wm + i * 16 + quad * 4;
            int n = n0 + wn + j * 16 + l16;
            float bv = bias[n];
            for (int r = 0; r < 4; r++) outp[(size_t)(mbase + r) * EMB + n] = acc[i][j][r] + bv;
        }
}

// ---------------------------------------------------------------- attention
// R18 = R17 structure with __launch_bounds__(256, 3).
// R15/R17 both spilled catastrophically at (256,4) (VGPR forced to 64 + 420-950
// MB scratch traffic) with DIFFERENT bodies; R13/R16 at (256,3) allocate 84
// VGPR cleanly -> hipcc's waves-per-EU=4 maps to a 64-VGPR cap for wave64.
// NEVER use the 4th tier here. At (256,3) the allocator gets ~170 headroom,
// uses ~84-96; 84<=128 means HW can still co-schedule 4 waves/SIMD, so the
// 16 KB LDS window (occupancy 34% measured even while spilling, vs 21-23% at
// 24 KB) can now pay without spill. Structure: Ks+Vs single-buffered (8 KB
// each); order SM(t) -> PV(t) -> barrier -> stage(t+1)/load(t+2) -> barrier
// -> QK(t+1); fine grid 12x136 = 1632 blocks (6.4 blocks/CU supply).
template <bool FINE>
__global__ __launch_bounds__(256, 3) void attn_kernel(const unsigned short* __restrict__ QKb,
                                                      const unsigned short* __restrict__ Vtb,
                                                      unsigned short* __restrict__ ctxb,
                                                      unsigned short* __restrict__ Op,
                                                      float* __restrict__ mArr,
                                                      float* __restrict__ lArr) {
    __shared__ __align__(16) unsigned short Ks[64 * 64];  // 8 KB
    __shared__ __align__(16) unsigned short Vs[64 * 64];  // 8 KB

    const int bid = blockIdx.x;
    const int h = bid % HEADS;
    int i128, ch, nch;
    if (FINE) {
        const int r2 = 135 - bid / HEADS;  // big i128 (long chunks) first
        if (r2 < 20) {
            i128 = r2 >> 1; ch = r2 & 1; nch = 2;
        } else if (r2 < 60) {
            int t = r2 - 20; i128 = 10 + (t >> 2); ch = t & 3; nch = 4;
        } else if (r2 < 120) {
            int t = r2 - 60; i128 = 20 + t / 6; ch = t % 6; nch = 6;
        } else {
            int t = r2 - 120; i128 = 30 + (t >> 3); ch = t & 7; nch = 8;
        }
    } else {
        const int r2 = 67 - bid / HEADS;  // big i128 (long chunks) first
        if (r2 < 10) {
            i128 = r2; ch = 0; nch = 1;
        } else if (r2 < 30) {
            int t = r2 - 10; i128 = 10 + (t >> 1); ch = t & 1; nch = 2;
        } else if (r2 < 60) {
            int t = r2 - 30; i128 = 20 + t / 3; ch = t % 3; nch = 3;
        } else {
            int t = r2 - 60; i128 = 30 + (t >> 2); ch = t & 3; nch = 4;
        }
    }
    const int T = 2 * i128 + 2;
    const int kb = ch * T / nch;
    const int ke = (ch + 1) * T / nch - 1;
    const int qbase = i128 * 128;
    const int tid = threadIdx.x;
    const int wave = tid >> 6, lane = tid & 63, quad = lane >> 4, l16 = lane & 15;

    const unsigned short* Qg = QKb + (size_t)h * HD;          // row stride 1536
    const unsigned short* Kg = QKb + (size_t)(EMB + h * HD);  // row stride 1536
    const unsigned short* Vh = Vtb + (size_t)h * HD * SEQ;    // [d][m]

    const int qa = qbase + wave * 32 + l16;  // set a: waves 0..3 cover 128 q-rows
    const int qb = qa + 16;                  // set b
    const short8 bQ0a = *(const short8*)&Qg[(size_t)qa * 1536 + quad * 8];
    const short8 bQ1a = *(const short8*)&Qg[(size_t)qa * 1536 + 32 + quad * 8];
    const short8 bQ0b = *(const short8*)&Qg[(size_t)qb * 1536 + quad * 8];
    const short8 bQ1b = *(const short8*)&Qg[(size_t)qb * 1536 + 32 + quad * 8];

    const int row = tid >> 2, t4 = tid & 3;  // 256 threads: 64 rows x 4 chunks
    const int swk = row & 7, swv = row & 15;

    f32x4 Oa[4] = {}, Ob[4] = {};
    float m_a = -3.0e38f, l_a = 0.f;
    float m_b = -3.0e38f, l_b = 0.f;

    uint4 kr0, kr1, vr0, vr1;
    {
        const int kb64 = kb * 64;
        const unsigned short* kp = &Kg[(size_t)(kb64 + row) * 1536];
        kr0 = *(const uint4*)&kp[(2 * t4) * 8];
        kr1 = *(const uint4*)&kp[(2 * t4 + 1) * 8];
        const unsigned short* vp = &Vh[(size_t)row * SEQ + kb64];
        vr0 = *(const uint4*)&vp[t4 * 16];
        vr1 = *(const uint4*)&vp[t4 * 16 + 8];
    }
    // tile kb -> Ks + Vs
    *(uint4*)&Ks[row * 64 + ((2 * t4) ^ swk) * 8] = kr0;
    *(uint4*)&Ks[row * 64 + ((2 * t4 + 1) ^ swk) * 8] = kr1;
    *(uint2*)&Vs[row * 64 + ((4 * t4) ^ swv) * 4] = ((const uint2*)&vr0)[0];
    *(uint2*)&Vs[row * 64 + ((4 * t4 + 1) ^ swv) * 4] = ((const uint2*)&vr0)[1];
    *(uint2*)&Vs[row * 64 + ((4 * t4 + 2) ^ swv) * 4] = ((const uint2*)&vr1)[0];
    *(uint2*)&Vs[row * 64 + ((4 * t4 + 3) ^ swv) * 4] = ((const uint2*)&vr1)[1];
    if (kb < ke) {
        const int nb = (kb + 1) * 64;
        const unsigned short* kp = &Kg[(size_t)(nb + row) * 1536];
        kr0 = *(const uint4*)&kp[(2 * t4) * 8];
        kr1 = *(const uint4*)&kp[(2 * t4 + 1) * 8];
        const unsigned short* vp = &Vh[(size_t)row * SEQ + nb];
        vr0 = *(const uint4*)&vp[t4 * 16];
        vr1 = *(const uint4*)&vp[t4 * 16 + 8];
    }
    __syncthreads();

    const int qw = qbase + wave * 32 + 31;  // wave's last causal q-row
    const int swr = l16 & 7;

    // prologue QK(kb) -> sa/sb (pipeline priming)
    f32x4 sa[4], sb[4];
    if (kb * 64 <= qw) {
        for (int nt = 0; nt < 4; nt++) {
            short8 aK0 = *(const short8*)&Ks[(nt * 16 + l16) * 64 + (quad ^ swr) * 8];
            short8 aK1 = *(const short8*)&Ks[(nt * 16 + l16) * 64 + ((quad + 4) ^ swr) * 8];
            f32x4 za = {};
            za = mfma32(aK0, bQ0a, za);
            za = mfma32(aK1, bQ1a, za);
            sa[nt] = za;
            f32x4 zb = {};
            zb = mfma32(aK0, bQ0b, zb);
            zb = mfma32(aK1, bQ1b, zb);
            sb[nt] = zb;
        }
        if (kb * 64 + 63 > qbase + wave * 32) {
            for (int nt = 0; nt < 4; nt++)
                for (int r = 0; r < 4; r++) {
                    const int kk = kb * 64 + nt * 16 + quad * 4 + r;
                    if (kk > qa) sa[nt][r] = -INFINITY;
                    if (kk > qb) sb[nt][r] = -INFINITY;
                }
        }
    }

    for (int kt = kb; kt <= ke; kt++) {
        const int kbase = kt * 64;
        const bool cur = (kbase <= qw);

        // SM(kt) then PV(kt): both consume tile-kt state before any overwrite
        if (cur) {
            short4v pka[4], pkb[4];
            softmax_q(sa, m_a, l_a, Oa, pka);
            softmax_q(sb, m_b, l_b, Ob, pkb);
            for (int dt = 0; dt < 4; dt++)
                for (int nt = 0; nt < 4; nt++) {
                    short4v av =
                        *(const short4v*)&Vs[(dt * 16 + l16) * 64 + ((4 * nt + quad) ^ l16) * 4];
                    Oa[dt] = mfma16(av, pka[nt], Oa[dt]);
                    Ob[dt] = mfma16(av, pkb[nt], Ob[dt]);
                }
        }

        __syncthreads();  // all waves done reading Ks(kt)/Vs(kt)
        if (kt < ke) {
            // stage tile kt+1 from regs; then issue loads for kt+2
            *(uint4*)&Ks[row * 64 + ((2 * t4) ^ swk) * 8] = kr0;
            *(uint4*)&Ks[row * 64 + ((2 * t4 + 1) ^ swk) * 8] = kr1;
            *(uint2*)&Vs[row * 64 + ((4 * t4) ^ swv) * 4] = ((const uint2*)&vr0)[0];
            *(uint2*)&Vs[row * 64 + ((4 * t4 + 1) ^ swv) * 4] = ((const uint2*)&vr0)[1];
            *(uint2*)&Vs[row * 64 + ((4 * t4 + 2) ^ swv) * 4] = ((const uint2*)&vr1)[0];
            *(uint2*)&Vs[row * 64 + ((4 * t4 + 3) ^ swv) * 4] = ((const uint2*)&vr1)[1];
            if (kt + 1 < ke) {
                const int nb = (kt + 2) * 64;
                const unsigned short* kp = &Kg[(size_t)(nb + row) * 1536];
                kr0 = *(const uint4*)&kp[(2 * t4) * 8];
                kr1 = *(const uint4*)&kp[(2 * t4 + 1) * 8];
                const unsigned short* vp = &Vh[(size_t)row * SEQ + nb];
                vr0 = *(const uint4*)&vp[t4 * 16];
                vr1 = *(const uint4*)&vp[t4 * 16 + 8];
            }
        }
        __syncthreads();  // tile kt+1 staged & visible

        // QK(kt+1): MFMA from freshly staged Ks; overlaps the kt+2 load latency
        const int kn = kbase + 64;
        if (kt < ke && kn <= qw) {
            for (int nt = 0; nt < 4; nt++) {
                short8 aK0 = *(const short8*)&Ks[(nt * 16 + l16) * 64 + (quad ^ swr) * 8];
                short8 aK1 = *(const short8*)&Ks[(nt * 16 + l16) * 64 + ((quad + 4) ^ swr) * 8];
                f32x4 za = {};
                za = mfma32(aK0, bQ0a, za);
                za = mfma32(aK1, bQ1a, za);
                sa[nt] = za;
                f32x4 zb = {};
                zb = mfma32(aK0, bQ0b, zb);
                zb = mfma32(aK1, bQ1b, zb);
                sb[nt] = zb;
            }
            if (kn + 63 > qbase + wave * 32) {
                for (int nt = 0; nt < 4; nt++)
                    for (int r = 0; r < 4; r++) {
                        const int kk = kn + nt * 16 + quad * 4 + r;
                        if (kk > qa) sa[nt][r] = -INFINITY;
                        if (kk > qb) sb[nt][r] = -INFINITY;
                    }
            }
        }
    }

    // deferred cross-lane l reduction (m is quad-uniform by construction)
    l_a += __shfl_xor(l_a, 16);
    l_a += __shfl_xor(l_a, 32);
    l_b += __shfl_xor(l_b, 16);
    l_b += __shfl_xor(l_b, 32);

    const int qla = wave * 32 + l16;  // 0..127 across 4 waves (set a)
    const int qlb = qla + 16;         // set b
    if (!FINE && nch == 1) {
        const float ia = 1.f / l_a, ib = 1.f / l_b;
        for (int dt = 0; dt < 4; dt++) {
            ushort4 oa, ob;
            oa.x = f2bf(Oa[dt][0] * ia);
            oa.y = f2bf(Oa[dt][1] * ia);
            oa.z = f2bf(Oa[dt][2] * ia);
            oa.w = f2bf(Oa[dt][3] * ia);
            ob.x = f2bf(Ob[dt][0] * ib);
            ob.y = f2bf(Ob[dt][1] * ib);
            ob.z = f2bf(Ob[dt][2] * ib);
            ob.w = f2bf(Ob[dt][3] * ib);
            *(ushort4*)&ctxb[(size_t)qa * EMB + h * HD + dt * 16 + quad * 4] = oa;
            *(ushort4*)&ctxb[(size_t)qb * EMB + h * HD + dt * 16 + quad * 4] = ob;
        }
    } else {
        if (ch == 0) {
            for (int dt = 0; dt < 4; dt++) {
                ushort4 oa, ob;
                oa.x = f2bf(Oa[dt][0]);
                oa.y = f2bf(Oa[dt][1]);
                oa.z = f2bf(Oa[dt][2]);
                oa.w = f2bf(Oa[dt][3]);
                ob.x = f2bf(Ob[dt][0]);
                ob.y = f2bf(Ob[dt][1]);
                ob.z = f2bf(Ob[dt][2]);
                ob.w = f2bf(Ob[dt][3]);
                *(ushort4*)&ctxb[(size_t)qa * EMB + h * HD + dt * 16 + quad * 4] = oa;
                *(ushort4*)&ctxb[(size_t)qb * EMB + h * HD + dt * 16 + quad * 4] = ob;
            }
        } else {
            const int pid = FINE ? pid_fine(h, i128, ch) : pid_coarse(h, i128, ch);
            for (int dt = 0; dt < 4; dt++) {
                ushort4 oa, ob;
                oa.x = f2bf(Oa[dt][0]);
                oa.y = f2bf(Oa[dt][1]);
                oa.z = f2bf(Oa[dt][2]);
                oa.w = f2bf(Oa[dt][3]);
                ob.x = f2bf(Ob[dt][0]);
                ob.y = f2bf(Ob[dt][1]);
                ob.z = f2bf(Ob[dt][2]);
                ob.w = f2bf(Ob[dt][3]);
                *(ushort4*)&Op[(size_t)pid * 8192 + qla * 64 + dt * 16 + quad * 4] = oa;
                *(ushort4*)&Op[(size_t)pid * 8192 + qlb * 64 + dt * 16 + quad * 4] = ob;
            }
        }
        if (quad == 0) {
            const int MLS = FINE ? 8 : 4;
            const int mlb = ((h * 32 + i128) * MLS + ch) * 128;
            mArr[mlb + qla] = m_a;
            lArr[mlb + qla] = l_a;
            mArr[mlb + qlb] = m_b;
            lArr[mlb + qlb] = l_b;
        }
    }
}

// ---------------------------------------------------------------- merge
// coarse: 264 blocks, i128 10..31, nch 2/3/4. fine: 384 blocks, i128 0..31,
// nch 2/4/6/8.
template <bool FINE>
__global__ __launch_bounds__(256) void merge_kernel(const unsigned short* __restrict__ Op,
                                                    const float* __restrict__ mArr,
                                                    const float* __restrict__ lArr,
                                                    unsigned short* __restrict__ ctxb) {
    const int gid = blockIdx.x;
    const int h = gid % HEADS;
    const int i128 = FINE ? (gid / HEADS) : (10 + gid / HEADS);
    int nch;
    if (FINE)
        nch = (i128 < 10) ? 2 : (i128 < 20) ? 4 : (i128 < 30) ? 6 : 8;
    else
        nch = (i128 < 20) ? 2 : (i128 < 30) ? 3 : 4;
    const int MLS = FINE ? 8 : 4;
    const int q = threadIdx.x >> 1, d0 = (threadIdx.x & 1) * 32;
    const int mlbase = (h * 32 + i128) * MLS;

    float mc[8], lc[8];
    for (int c = 0; c < nch; c++) {
        mc[c] = mArr[(mlbase + c) * 128 + q];
        lc[c] = lArr[(mlbase + c) * 128 + q];
    }
    float M = mc[0];
    for (int c = 1; c < nch; c++) M = fmaxf(M, mc[c]);
    float w[8], L = 0.f;
    for (int c = 0; c < nch; c++) {
        w[c] = __builtin_amdgcn_exp2f(mc[c] - M);
        L += w[c] * lc[c];
    }
    const float inv = 1.f / L;
    for (int c = 0; c < nch; c++) w[c] *= inv;

    unsigned short* dst = &ctxb[(size_t)(i128 * 128 + q) * EMB + h * HD + d0];
    for (int jj = 0; jj < 32; jj += 8) {
        uint4 u0 = *(const uint4*)&dst[jj];  // chunk0 (unnormalized) in place
        float f[8];
        const unsigned short* p0 = (const unsigned short*)&u0;
        for (int t = 0; t < 8; t++)
            f[t] = w[0] * __builtin_bit_cast(float, (unsigned int)p0[t] << 16);
        for (int c = 1; c < nch; c++) {
            const int pid = FINE ? pid_fine(h, i128, c) : pid_coarse(h, i128, c);
            uint4 u = *(const uint4*)&Op[(size_t)pid * 8192 + q * 64 + d0 + jj];
            const unsigned short* p = (const unsigned short*)&u;
            for (int t = 0; t < 8; t++)
                f[t] += w[c] * __builtin_bit_cast(float, (unsigned int)p[t] << 16);
        }
        unsigned short o[8];
        for (int t = 0; t < 8; t++) o[t] = f2bf(f[t]);
        *(uint4*)&dst[jj] = *(uint4*)o;
    }
}

// ---------------------------------------------------------------- launch
extern "C" void kernel_launch(void* const* d_in, const int* in_sizes, int n_in,
                              void* d_out, int out_size, void* d_ws, size_t ws_size,
                              hipStream_t stream) {
    const float* x = (const float*)d_in[0];
    const float* wq = (const float*)d_in[1];
    const float* bq = (const float*)d_in[2];
    const float* wk = (const float*)d_in[3];
    const float* bk = (const float*)d_in[4];
    const float* wv = (const float*)d_in[5];
    const float* bv = (const float*)d_in[6];
    const float* wo = (const float*)d_in[7];
    const float* bo = (const float*)d_in[8];

    unsigned short* ws = (unsigned short*)d_ws;
    unsigned short* xb = ws;                          // 3,145,728 ush
    unsigned short* wqkvT = xb + SEQ * EMB;           // 1,769,472
    unsigned short* woT = wqkvT + 3 * EMB * EMB;      // 589,824
    unsigned short* QKb = woT + EMB * EMB;            // 4096*1536 -> ends 11,796,480
    unsigned short* Vtb = QKb + (size_t)SEQ * 1536;   // 3,145,728 -> ends 14,942,208
    unsigned short* ctxb = Vtb + HEADS * SEQ * HD;    // 3,145,728 -> ends 18,087,936

    convert_all<<<dim3(3072 + 576), 256, 0, stream>>>(x, wq, wk, wv, wo, xb, wqkvT, woT);
    gemm_qkv<<<dim3(SEQ / 128, 3 * EMB / 128), 256, 0, stream>>>(
        xb, wqkvT, bq, bk, bv, QKb, Vtb);

    // fine layout lives past the base workspace end (ctxb end = 18,087,936 ush):
    //   OpF   1248 * 8192            = 10,223,616 ush -> ends 28,311,552
    //   mArrF 393,216 f32            =    786,432 ush -> ends 29,097,984
    //   lArrF 393,216 f32            =    786,432 ush -> ends 29,884,416  (59.77 MB)
    const bool fine = ws_size >= (size_t)29884416 * 2;
    if (fine) {
        unsigned short* OpF = ws + 18087936u;
        float* mF = (float*)(ws + 28311552u);
        float* lF = mF + 393216;
        attn_kernel<true><<<dim3(12 * 136), 256, 0, stream>>>(QKb, Vtb, ctxb, OpF, mF, lF);
        merge_kernel<true><<<dim3(12 * 32), 256, 0, stream>>>(OpF, mF, lF, ctxb);
    } else {
        // coarse scratch aliases xb+wqkvT (dead after gemm_qkv):
        // Op 432*8192 = 3,538,944 ush; mArr/lArr 196,608 f32 each
        unsigned short* Op = xb;
        float* mArr = (float*)(ws + 3538944);
        float* lArr = mArr + 196608;
        attn_kernel<false><<<dim3(12 * 68), 256, 0, stream>>>(QKb, Vtb, ctxb, Op, mArr, lArr);
        merge_kernel<false><<<dim3(264), 256, 0, stream>>>(Op, mArr, lArr, ctxb);
    }
    gemm_out<<<dim3(SEQ / 64, EMB / 128), 256, 0, stream>>>(ctxb, woT, bo, (float*)d_out);
}

// Round 9
// 182.826 us; speedup vs baseline: 1.4585x; 1.0532x over previous
//
#include <hip/hip_runtime.h>
#include <stdint.h>

#define SEQ 4096
#define EMB 768
#define HEADS 12
#define HD 64

typedef __attribute__((ext_vector_type(8))) short short8;
typedef __attribute__((ext_vector_type(4))) short short4v;
typedef __attribute__((ext_vector_type(8))) __bf16 bf16x8;
typedef __attribute__((ext_vector_type(4))) __bf16 bf16x4;
typedef __attribute__((ext_vector_type(4))) float f32x4;

// scale * log2(e) folded into Q: (1/sqrt(64)) * 1.4426950408889634
#define QSCALE 0.18033688011112043f

static __device__ __forceinline__ unsigned short f2bf(float f) {
    unsigned int u = __builtin_bit_cast(unsigned int, f);
    unsigned int r = 0x7fffu + ((u >> 16) & 1u);
    u += r;
    return (unsigned short)(u >> 16);
}

static __device__ __forceinline__ f32x4 mfma32(short8 a, short8 b, f32x4 c) {
    return __builtin_amdgcn_mfma_f32_16x16x32_bf16(
        __builtin_bit_cast(bf16x8, a), __builtin_bit_cast(bf16x8, b), c, 0, 0, 0);
}

static __device__ __forceinline__ f32x4 mfma16(short4v a, short4v b, f32x4 c) {
#if __has_builtin(__builtin_amdgcn_mfma_f32_16x16x16_bf16)
    return __builtin_amdgcn_mfma_f32_16x16x16_bf16(
        __builtin_bit_cast(bf16x4, a), __builtin_bit_cast(bf16x4, b), c, 0, 0, 0);
#else
    return __builtin_amdgcn_mfma_f32_16x16x16bf16_1k(a, b, c, 0, 0, 0);
#endif
}

static __device__ __forceinline__ short4v pack4bf(float a, float b, float c, float d) {
#if __has_builtin(__builtin_amdgcn_cvt_pk_bf16_f32)
    typedef __attribute__((ext_vector_type(2))) __bf16 bf16x2;
    bf16x2 lo = __builtin_amdgcn_cvt_pk_bf16_f32(a, b);
    bf16x2 hi = __builtin_amdgcn_cvt_pk_bf16_f32(c, d);
    uint2 u = {__builtin_bit_cast(unsigned int, lo), __builtin_bit_cast(unsigned int, hi)};
    return __builtin_bit_cast(short4v, u);
#else
    short4v p;
    p[0] = (short)f2bf(a); p[1] = (short)f2bf(b);
    p[2] = (short)f2bf(c); p[3] = (short)f2bf(d);
    return p;
#endif
}

static __device__ __forceinline__ void load_lds16(const void* g, void* l) {
    __builtin_amdgcn_global_load_lds(
        (const __attribute__((address_space(1))) unsigned int*)(uintptr_t)g,
        (__attribute__((address_space(3))) unsigned int*)(uintptr_t)l, 16, 0, 0);
}

// partial-id for (h, i128, ch>=1); 36 slots/head, 432 total
static __device__ __forceinline__ int pid_of(int h, int i128, int ch) {
    int b = (i128 < 20) ? (i128 - 10)
                        : (i128 < 30 ? 10 + (i128 - 20) * 2 : 30 + (i128 - 30) * 3);
    return h * 36 + b + (ch - 1);
}

// online-softmax step over one 64-k tile held as st[4] (S^T layout).
// Common path is LANE-LOCAL only (15-op fmax tree). Cross-quad reduce +
// rescale live inside the rare defer-max branch. m_i stays quad-uniform by
// induction, so P fed to the k-spanning PV MFMA is consistently normalized.
static __device__ __forceinline__ void softmax_q(f32x4* st, float& m_i, float& l_i,
                                                 f32x4* O, short4v* pk) {
    float t0 = fmaxf(fmaxf(st[0][0], st[0][1]), fmaxf(st[0][2], st[0][3]));
    float t1 = fmaxf(fmaxf(st[1][0], st[1][1]), fmaxf(st[1][2], st[1][3]));
    float t2 = fmaxf(fmaxf(st[2][0], st[2][1]), fmaxf(st[2][2], st[2][3]));
    float t3 = fmaxf(fmaxf(st[3][0], st[3][1]), fmaxf(st[3][2], st[3][3]));
    float mx = fmaxf(fmaxf(t0, t1), fmaxf(t2, t3));  // this lane's 16 values
    if (__ballot(mx > m_i + 5.0f)) {  // rare after warm-up
        mx = fmaxf(mx, __shfl_xor(mx, 16));
        mx = fmaxf(mx, __shfl_xor(mx, 32));  // per-q (cross-quad) max
        const bool inc = mx > m_i;
        const float mn = inc ? mx : m_i;
        const float alpha = __builtin_amdgcn_exp2f(m_i - mn);
        m_i = mn;
        l_i *= alpha;
        for (int dt = 0; dt < 4; dt++)
            for (int r = 0; r < 4; r++) O[dt][r] *= alpha;
    }
    float rs = 0.f;
    for (int nt = 0; nt < 4; nt++) {
        float p0 = __builtin_amdgcn_exp2f(st[nt][0] - m_i);
        float p1 = __builtin_amdgcn_exp2f(st[nt][1] - m_i);
        float p2 = __builtin_amdgcn_exp2f(st[nt][2] - m_i);
        float p3 = __builtin_amdgcn_exp2f(st[nt][3] - m_i);
        rs += p0 + p1 + p2 + p3;
        pk[nt] = pack4bf(p0, p1, p2, p3);
    }
    l_i += rs;  // per-lane partial; reduced across quads at epilogue
}

// ---------------------------------------------------------------- fused convert
__global__ __launch_bounds__(256) void convert_all(const float* __restrict__ x,
                                                   const float* __restrict__ wq,
                                                   const float* __restrict__ wk,
                                                   const float* __restrict__ wv,
                                                   const float* __restrict__ wo,
                                                   unsigned short* __restrict__ xb,
                                                   unsigned short* __restrict__ wqkvT,
                                                   unsigned short* __restrict__ woT) {
    __shared__ float Ls[64][65];
    const int bid = blockIdx.x;
    if (bid < 3072) {
        int i = bid * 256 + threadIdx.x;
        float4 v = ((const float4*)x)[i];
        ushort4 o = {f2bf(v.x), f2bf(v.y), f2bf(v.z), f2bf(v.w)};
        ((ushort4*)xb)[i] = o;
        return;
    }
    const int idx = bid - 3072;
    const int z = idx / 144;
    const int bx = (idx % 144) / 12, by = idx % 12;
    const float* W = (z == 0) ? wq : (z == 1) ? wk : (z == 2) ? wv : wo;
    unsigned short* dst = (z < 3) ? (wqkvT + (size_t)z * EMB * EMB) : woT;
    const int k0 = bx * 64, n0 = by * 64;
    const int r = threadIdx.x >> 2, c0 = (threadIdx.x & 3) * 16;
    for (int j = 0; j < 16; j += 4) {
        float4 v = *(const float4*)&W[(size_t)(k0 + r) * EMB + n0 + c0 + j];
        Ls[r][c0 + j] = v.x;
        Ls[r][c0 + j + 1] = v.y;
        Ls[r][c0 + j + 2] = v.z;
        Ls[r][c0 + j + 3] = v.w;
    }
    __syncthreads();
    unsigned short tmp[16];
    for (int j = 0; j < 16; j++) tmp[j] = f2bf(Ls[c0 + j][r]);
    *(uint4*)&dst[(size_t)(n0 + r) * EMB + k0 + c0] = *(uint4*)tmp;
    *(uint4*)&dst[(size_t)(n0 + r) * EMB + k0 + c0 + 8] = *(uint4*)(tmp + 8);
}

// ---------------------------------------------------------------- 64x128 QKV GEMM
// R19: tile 128x128 -> 64x128. Grid (64,18) = 1152 blocks (was 384 = 1.5
// blocks/CU supply — the lowest-TLP kernel in the pipeline; same latency-bound
// disease as attn). Loop structure mirrors the proven gemm_out BK=32
// double-buffered DMA loop. 24 KB LDS.
__global__ __launch_bounds__(256) void gemm_qkv(const unsigned short* __restrict__ A,
                                                const unsigned short* __restrict__ Bt,
                                                const float* __restrict__ b0p,
                                                const float* __restrict__ b1p,
                                                const float* __restrict__ b2p,
                                                unsigned short* __restrict__ QKb,
                                                unsigned short* __restrict__ Vtb) {
    __shared__ __align__(16) unsigned short SMEM[12288];  // As[2]@0/2048, Bs[2]@4096/8192
    const int tid = threadIdx.x;
    const int wave = tid >> 6, lane = tid & 63, quad = lane >> 4, l16 = lane & 15;
    const int m0 = blockIdx.x * 64, n0 = blockIdx.y * 128;
    const int wm = (wave >> 1) * 32, wn = (wave & 1) * 64;
    const int lrow = lane >> 2, lcol = (lane & 3) * 8;

    f32x4 acc[2][4] = {};

    load_lds16(&A[(size_t)(m0 + wave * 16 + lrow) * EMB + lcol], &SMEM[wave * 512]);
    for (int t = 0; t < 2; t++) {
        int row = wave * 32 + t * 16 + lrow;
        load_lds16(&Bt[(size_t)(n0 + row) * EMB + lcol], &SMEM[4096 + (wave * 2 + t) * 512]);
    }
    int buf = 0;
    for (int k0 = 0; k0 < EMB; k0 += 32) {
        __syncthreads();
        if (k0 + 32 < EMB) {
            unsigned short* A_ = &SMEM[(buf ^ 1) * 2048];
            unsigned short* B_ = &SMEM[4096 + (buf ^ 1) * 4096];
            load_lds16(&A[(size_t)(m0 + wave * 16 + lrow) * EMB + k0 + 32 + lcol], &A_[wave * 512]);
            for (int t = 0; t < 2; t++) {
                int row = wave * 32 + t * 16 + lrow;
                load_lds16(&Bt[(size_t)(n0 + row) * EMB + k0 + 32 + lcol], &B_[(wave * 2 + t) * 512]);
            }
        }
        const unsigned short* A_ = &SMEM[buf * 2048];
        const unsigned short* B_ = &SMEM[4096 + buf * 4096];
        short8 a[2], b[4];
        for (int i = 0; i < 2; i++) a[i] = *(const short8*)&A_[(wm + i * 16 + l16) * 32 + quad * 8];
        for (int j = 0; j < 4; j++) b[j] = *(const short8*)&B_[(wn + j * 16 + l16) * 32 + quad * 8];
        for (int i = 0; i < 2; i++)
            for (int j = 0; j < 4; j++) acc[i][j] = mfma32(a[i], b[j], acc[i][j]);
        buf ^= 1;
    }

    const int z = n0 / EMB;  // block-uniform: 0=Q, 1=K, 2=V
    if (z < 2) {
        const float* bias = z ? b1p : b0p;
        const float sc = z ? 1.0f : QSCALE;
        for (int i = 0; i < 2; i++)
            for (int j = 0; j < 4; j++) {
                int mbase = m0 + wm + i * 16 + quad * 4;
                int n = n0 + wn + j * 16 + l16;  // 0..1535 natural col
                float bv = bias[n - z * EMB];
                for (int r = 0; r < 4; r++)
                    QKb[(size_t)(mbase + r) * 1536 + n] = f2bf((acc[i][j][r] + bv) * sc);
            }
    } else {
        // V^T epilogue for 64-row tiles: per j-slab, 32 columns x 64 m-values
        // staged in SMEM (stride 72 ush = 36 dwords ≡ 4 mod 32 — same
        // conflict-free pattern as the original 136), then copied out as one
        // uint4 per thread: 32 cols (nl) x 8 chunks (c) of 8 ush.
        const int nn = n0 + wn + l16 - 2 * EMB;
        for (int j = 0; j < 4; j++) {
            __syncthreads();
            const float bv = b2p[nn + j * 16];
            const int nloc = (wave & 1) * 16 + l16;
            for (int i = 0; i < 2; i++) {
                ushort4 pk;
                pk.x = f2bf(acc[i][j][0] + bv);
                pk.y = f2bf(acc[i][j][1] + bv);
                pk.z = f2bf(acc[i][j][2] + bv);
                pk.w = f2bf(acc[i][j][3] + bv);
                *(ushort4*)&SMEM[nloc * 72 + wm + i * 16 + quad * 4] = pk;
            }
            __syncthreads();
            const int nl = tid >> 3, c = tid & 7;
            const int ng = (nl >> 4) * 64 + j * 16 + (nl & 15) + n0 - 2 * EMB;
            const int hh = ng >> 6, dd = ng & 63;
            unsigned short* dst = &Vtb[(size_t)(hh * HD + dd) * SEQ + m0];
            *(uint4*)&dst[c * 8] = *(uint4*)&SMEM[nl * 72 + c * 8];
        }
    }
}

// ---------------------------------------------------------------- 64x64 out-proj GEMM
// R19: tile 64x128 -> 64x64. Grid (64,12) = 768 blocks (was 384 = 1.5
// blocks/CU). 16 KB LDS.
__global__ __launch_bounds__(256) void gemm_out(const unsigned short* __restrict__ A,
                                                const unsigned short* __restrict__ Bt,
                                                const float* __restrict__ bias,
                                                float* __restrict__ outp) {
    __shared__ __align__(16) unsigned short SMEM[8192];  // As[2]@0/2048, Bs[2]@4096/6144
    const int tid = threadIdx.x;
    const int wave = tid >> 6, lane = tid & 63, quad = lane >> 4, l16 = lane & 15;
    const int m0 = blockIdx.x * 64, n0 = blockIdx.y * 64;
    const int wm = (wave >> 1) * 32, wn = (wave & 1) * 32;
    const int lrow = lane >> 2, lcol = (lane & 3) * 8;

    f32x4 acc[2][2] = {};

    load_lds16(&A[(size_t)(m0 + wave * 16 + lrow) * EMB + lcol], &SMEM[wave * 512]);
    load_lds16(&Bt[(size_t)(n0 + wave * 16 + lrow) * EMB + lcol], &SMEM[4096 + wave * 512]);
    int buf = 0;
    for (int k0 = 0; k0 < EMB; k0 += 32) {
        __syncthreads();
        if (k0 + 32 < EMB) {
            unsigned short* A_ = &SMEM[(buf ^ 1) * 2048];
            unsigned short* B_ = &SMEM[4096 + (buf ^ 1) * 2048];
            load_lds16(&A[(size_t)(m0 + wave * 16 + lrow) * EMB + k0 + 32 + lcol], &A_[wave * 512]);
            load_lds16(&Bt[(size_t)(n0 + wave * 16 + lrow) * EMB + k0 + 32 + lcol], &B_[wave * 512]);
        }
        const unsigned short* A_ = &SMEM[buf * 2048];
        const unsigned short* B_ = &SMEM[4096 + buf * 2048];
        short8 a[2], b[2];
        for (int i = 0; i < 2; i++) a[i] = *(const short8*)&A_[(wm + i * 16 + l16) * 32 + quad * 8];
        for (int j = 0; j < 2; j++) b[j] = *(const short8*)&B_[(wn + j * 16 + l16) * 32 + quad * 8];
        for (int i = 0; i < 2; i++)
            for (int j = 0; j < 2; j++) acc[i][j] = mfma32(a[i], b[j], acc[i][j]);
        buf ^= 1;
    }

    for (int i = 0; i < 2; i++)
        for (int j = 0; j < 2; j++) {
            int mbase = m0 + wm + i * 16 + quad * 4;
            int n = n0 + wn + j * 16 + l16;
            float bv = bias[n];
            for (int r = 0; r < 4; r++) outp[(size_t)(mbase + r) * EMB + n] = acc[i][j][r] + bv;
        }
}

// ---------------------------------------------------------------- attention
// R19 attn = R13 exact (best measured: 55.6 us; the only attn change that ever
// paid was this software-pipelining, -12%). 816 blocks = 12 heads x 68 chunks;
// 256 threads = 4 waves x 32 q-rows (2 fragment sets/wave); SM(t) || QK(t+1)
// || PV(t); K single-buf + V double-buf = 24 KB LDS; 2 barriers/tile; (256,3)
// (NEVER (256,4): hipcc maps the 4th tier to a 64-VGPR cap -> catastrophic
// spill, measured twice). Occupancy is pinned ~8 waves/CU regardless of LDS
// (16/24/32 KB all equal) — stop chasing it.
__global__ __launch_bounds__(256, 3) void attn_kernel(const unsigned short* __restrict__ QKb,
                                                      const unsigned short* __restrict__ Vtb,
                                                      unsigned short* __restrict__ ctxb,
                                                      unsigned short* __restrict__ Op,
                                                      float* __restrict__ mArr,
                                                      float* __restrict__ lArr) {
    __shared__ __align__(16) unsigned short Ks[64 * 64];
    __shared__ __align__(16) unsigned short Vs[2][64 * 64];

    const int bid = blockIdx.x;
    const int h = bid % HEADS;
    const int r2 = 67 - bid / HEADS;  // big i128 (long chunks) first
    int i128, ch, nch;
    if (r2 < 10) {
        i128 = r2; ch = 0; nch = 1;
    } else if (r2 < 30) {
        int t = r2 - 10; i128 = 10 + (t >> 1); ch = t & 1; nch = 2;
    } else if (r2 < 60) {
        int t = r2 - 30; i128 = 20 + t / 3; ch = t % 3; nch = 3;
    } else {
        int t = r2 - 60; i128 = 30 + (t >> 2); ch = t & 3; nch = 4;
    }
    const int T = 2 * i128 + 2;
    const int kb = ch * T / nch;
    const int ke = (ch + 1) * T / nch - 1;
    const int qbase = i128 * 128;
    const int tid = threadIdx.x;
    const int wave = tid >> 6, lane = tid & 63, quad = lane >> 4, l16 = lane & 15;

    const unsigned short* Qg = QKb + (size_t)h * HD;          // row stride 1536
    const unsigned short* Kg = QKb + (size_t)(EMB + h * HD);  // row stride 1536
    const unsigned short* Vh = Vtb + (size_t)h * HD * SEQ;    // [d][m]

    const int qa = qbase + wave * 32 + l16;  // set a: waves 0..3 cover 128 q-rows
    const int qb = qa + 16;                  // set b
    const short8 bQ0a = *(const short8*)&Qg[(size_t)qa * 1536 + quad * 8];
    const short8 bQ1a = *(const short8*)&Qg[(size_t)qa * 1536 + 32 + quad * 8];
    const short8 bQ0b = *(const short8*)&Qg[(size_t)qb * 1536 + quad * 8];
    const short8 bQ1b = *(const short8*)&Qg[(size_t)qb * 1536 + 32 + quad * 8];

    const int row = tid >> 2, t4 = tid & 3;  // 256 threads: 64 rows x 4 chunks
    const int swk = row & 7, swv = row & 15;

    f32x4 Oa[4] = {}, Ob[4] = {};
    float m_a = -3.0e38f, l_a = 0.f;
    float m_b = -3.0e38f, l_b = 0.f;

    uint4 kr0, kr1, vr0, vr1;
    {
        const int kb64 = kb * 64;
        const unsigned short* kp = &Kg[(size_t)(kb64 + row) * 1536];
        kr0 = *(const uint4*)&kp[(2 * t4) * 8];
        kr1 = *(const uint4*)&kp[(2 * t4 + 1) * 8];
        const unsigned short* vp = &Vh[(size_t)row * SEQ + kb64];
        vr0 = *(const uint4*)&vp[t4 * 16];
        vr1 = *(const uint4*)&vp[t4 * 16 + 8];
    }
    // tile kb -> Ks + Vs[0]
    *(uint4*)&Ks[row * 64 + ((2 * t4) ^ swk) * 8] = kr0;
    *(uint4*)&Ks[row * 64 + ((2 * t4 + 1) ^ swk) * 8] = kr1;
    *(uint2*)&Vs[0][row * 64 + ((4 * t4) ^ swv) * 4] = ((const uint2*)&vr0)[0];
    *(uint2*)&Vs[0][row * 64 + ((4 * t4 + 1) ^ swv) * 4] = ((const uint2*)&vr0)[1];
    *(uint2*)&Vs[0][row * 64 + ((4 * t4 + 2) ^ swv) * 4] = ((const uint2*)&vr1)[0];
    *(uint2*)&Vs[0][row * 64 + ((4 * t4 + 3) ^ swv) * 4] = ((const uint2*)&vr1)[1];
    if (kb < ke) {
        const int nb = (kb + 1) * 64;
        const unsigned short* kp = &Kg[(size_t)(nb + row) * 1536];
        kr0 = *(const uint4*)&kp[(2 * t4) * 8];
        kr1 = *(const uint4*)&kp[(2 * t4 + 1) * 8];
        const unsigned short* vp = &Vh[(size_t)row * SEQ + nb];
        vr0 = *(const uint4*)&vp[t4 * 16];
        vr1 = *(const uint4*)&vp[t4 * 16 + 8];
    }
    __syncthreads();

    const int qw = qbase + wave * 32 + 31;  // wave's last causal q-row
    const int swr = l16 & 7;

    // prologue QK(kb) -> sa/sb (pipeline priming)
    f32x4 sa[4], sb[4];
    if (kb * 64 <= qw) {
        for (int nt = 0; nt < 4; nt++) {
            short8 aK0 = *(const short8*)&Ks[(nt * 16 + l16) * 64 + (quad ^ swr) * 8];
            short8 aK1 = *(const short8*)&Ks[(nt * 16 + l16) * 64 + ((quad + 4) ^ swr) * 8];
            f32x4 za = {};
            za = mfma32(aK0, bQ0a, za);
            za = mfma32(aK1, bQ1a, za);
            sa[nt] = za;
            f32x4 zb = {};
            zb = mfma32(aK0, bQ0b, zb);
            zb = mfma32(aK1, bQ1b, zb);
            sb[nt] = zb;
        }
        if (kb * 64 + 63 > qbase + wave * 32) {
            for (int nt = 0; nt < 4; nt++)
                for (int r = 0; r < 4; r++) {
                    const int kk = kb * 64 + nt * 16 + quad * 4 + r;
                    if (kk > qa) sa[nt][r] = -INFINITY;
                    if (kk > qb) sb[nt][r] = -INFINITY;
                }
        }
    }

    int p = 0;  // Vs buffer holding the current PV tile
    for (int kt = kb; kt <= ke; kt++) {
        __syncthreads();  // all waves done: QK(kt) reads of Ks, PV(kt-1) reads of Vs[p^1]
        if (kt < ke) {
            // stage tile kt+1: K -> Ks (single buf), V -> Vs[p^1]
            *(uint4*)&Ks[row * 64 + ((2 * t4) ^ swk) * 8] = kr0;
            *(uint4*)&Ks[row * 64 + ((2 * t4 + 1) ^ swk) * 8] = kr1;
            *(uint2*)&Vs[p ^ 1][row * 64 + ((4 * t4) ^ swv) * 4] = ((const uint2*)&vr0)[0];
            *(uint2*)&Vs[p ^ 1][row * 64 + ((4 * t4 + 1) ^ swv) * 4] = ((const uint2*)&vr0)[1];
            *(uint2*)&Vs[p ^ 1][row * 64 + ((4 * t4 + 2) ^ swv) * 4] = ((const uint2*)&vr1)[0];
            *(uint2*)&Vs[p ^ 1][row * 64 + ((4 * t4 + 3) ^ swv) * 4] = ((const uint2*)&vr1)[1];
            if (kt + 1 < ke) {
                const int nb = (kt + 2) * 64;
                const unsigned short* kp = &Kg[(size_t)(nb + row) * 1536];
                kr0 = *(const uint4*)&kp[(2 * t4) * 8];
                kr1 = *(const uint4*)&kp[(2 * t4 + 1) * 8];
                const unsigned short* vp = &Vh[(size_t)row * SEQ + nb];
                vr0 = *(const uint4*)&vp[t4 * 16];
                vr1 = *(const uint4*)&vp[t4 * 16 + 8];
            }
        }
        __syncthreads();  // tile kt+1 staged & visible

        const int kbase = kt * 64;
        const bool cur = (kbase <= qw);

        // SM(kt): pure VALU on registers computed last iteration
        short4v pka[4], pkb[4];
        if (cur) {
            softmax_q(sa, m_a, l_a, Oa, pka);
            softmax_q(sb, m_b, l_b, Ob, pkb);
        }

        // QK(kt+1): MFMA from freshly staged Ks; overlaps SM's exp/pack tail
        const int kn = kbase + 64;
        if (kt < ke && kn <= qw) {
            for (int nt = 0; nt < 4; nt++) {
                short8 aK0 = *(const short8*)&Ks[(nt * 16 + l16) * 64 + (quad ^ swr) * 8];
                short8 aK1 = *(const short8*)&Ks[(nt * 16 + l16) * 64 + ((quad + 4) ^ swr) * 8];
                f32x4 za = {};
                za = mfma32(aK0, bQ0a, za);
                za = mfma32(aK1, bQ1a, za);
                sa[nt] = za;
                f32x4 zb = {};
                zb = mfma32(aK0, bQ0b, zb);
                zb = mfma32(aK1, bQ1b, zb);
                sb[nt] = zb;
            }
            if (kn + 63 > qbase + wave * 32) {
                for (int nt = 0; nt < 4; nt++)
                    for (int r = 0; r < 4; r++) {
                        const int kk = kn + nt * 16 + quad * 4 + r;
                        if (kk > qa) sa[nt][r] = -INFINITY;
                        if (kk > qb) sb[nt][r] = -INFINITY;
                    }
            }
        }

        // PV(kt): depends on pk; V fragments shared by both sets
        if (cur) {
            for (int dt = 0; dt < 4; dt++)
                for (int nt = 0; nt < 4; nt++) {
                    short4v av =
                        *(const short4v*)&Vs[p][(dt * 16 + l16) * 64 + ((4 * nt + quad) ^ l16) * 4];
                    Oa[dt] = mfma16(av, pka[nt], Oa[dt]);
                    Ob[dt] = mfma16(av, pkb[nt], Ob[dt]);
                }
        }

        p ^= 1;
    }

    // deferred cross-lane l reduction (m is quad-uniform by construction)
    l_a += __shfl_xor(l_a, 16);
    l_a += __shfl_xor(l_a, 32);
    l_b += __shfl_xor(l_b, 16);
    l_b += __shfl_xor(l_b, 32);

    const int qla = wave * 32 + l16;  // 0..127 across 4 waves (set a)
    const int qlb = qla + 16;         // set b
    if (nch == 1) {
        const float ia = 1.f / l_a, ib = 1.f / l_b;
        for (int dt = 0; dt < 4; dt++) {
            ushort4 oa, ob;
            oa.x = f2bf(Oa[dt][0] * ia);
            oa.y = f2bf(Oa[dt][1] * ia);
            oa.z = f2bf(Oa[dt][2] * ia);
            oa.w = f2bf(Oa[dt][3] * ia);
            ob.x = f2bf(Ob[dt][0] * ib);
            ob.y = f2bf(Ob[dt][1] * ib);
            ob.z = f2bf(Ob[dt][2] * ib);
            ob.w = f2bf(Ob[dt][3] * ib);
            *(ushort4*)&ctxb[(size_t)qa * EMB + h * HD + dt * 16 + quad * 4] = oa;
            *(ushort4*)&ctxb[(size_t)qb * EMB + h * HD + dt * 16 + quad * 4] = ob;
        }
    } else {
        if (ch == 0) {
            for (int dt = 0; dt < 4; dt++) {
                ushort4 oa, ob;
                oa.x = f2bf(Oa[dt][0]);
                oa.y = f2bf(Oa[dt][1]);
                oa.z = f2bf(Oa[dt][2]);
                oa.w = f2bf(Oa[dt][3]);
                ob.x = f2bf(Ob[dt][0]);
                ob.y = f2bf(Ob[dt][1]);
                ob.z = f2bf(Ob[dt][2]);
                ob.w = f2bf(Ob[dt][3]);
                *(ushort4*)&ctxb[(size_t)qa * EMB + h * HD + dt * 16 + quad * 4] = oa;
                *(ushort4*)&ctxb[(size_t)qb * EMB + h * HD + dt * 16 + quad * 4] = ob;
            }
        } else {
            const int pid = pid_of(h, i128, ch);
            for (int dt = 0; dt < 4; dt++) {
                ushort4 oa, ob;
                oa.x = f2bf(Oa[dt][0]);
                oa.y = f2bf(Oa[dt][1]);
                oa.z = f2bf(Oa[dt][2]);
                oa.w = f2bf(Oa[dt][3]);
                ob.x = f2bf(Ob[dt][0]);
                ob.y = f2bf(Ob[dt][1]);
                ob.z = f2bf(Ob[dt][2]);
                ob.w = f2bf(Ob[dt][3]);
                *(ushort4*)&Op[(size_t)pid * 8192 + qla * 64 + dt * 16 + quad * 4] = oa;
                *(ushort4*)&Op[(size_t)pid * 8192 + qlb * 64 + dt * 16 + quad * 4] = ob;
            }
        }
        if (quad == 0) {
            const int mlb = ((h * 32 + i128) * 4 + ch) * 128;
            mArr[mlb + qla] = m_a;
            lArr[mlb + qla] = l_a;
            mArr[mlb + qlb] = m_b;
            lArr[mlb + qlb] = l_b;
        }
    }
}

// ---------------------------------------------------------------- merge (i128>=10)
__global__ __launch_bounds__(256) void merge_kernel(const unsigned short* __restrict__ Op,
                                                    const float* __restrict__ mArr,
                                                    const float* __restrict__ lArr,
                                                    unsigned short* __restrict__ ctxb) {
    const int gid = blockIdx.x;  // 0..263
    const int h = gid % HEADS;
    const int i128 = 10 + gid / HEADS;
    const int nch = (i128 < 20) ? 2 : (i128 < 30) ? 3 : 4;
    const int q = threadIdx.x >> 1, d0 = (threadIdx.x & 1) * 32;
    const int mlbase = (h * 32 + i128) * 4;

    float mc[4], lc[4];
    for (int c = 0; c < nch; c++) {
        mc[c] = mArr[(mlbase + c) * 128 + q];
        lc[c] = lArr[(mlbase + c) * 128 + q];
    }
    float M = mc[0];
    for (int c = 1; c < nch; c++) M = fmaxf(M, mc[c]);
    float w[4], L = 0.f;
    for (int c = 0; c < nch; c++) {
        w[c] = __builtin_amdgcn_exp2f(mc[c] - M);
        L += w[c] * lc[c];
    }
    const float inv = 1.f / L;
    for (int c = 0; c < nch; c++) w[c] *= inv;

    unsigned short* dst = &ctxb[(size_t)(i128 * 128 + q) * EMB + h * HD + d0];
    for (int jj = 0; jj < 32; jj += 8) {
        uint4 u0 = *(const uint4*)&dst[jj];  // chunk0 (unnormalized) in place
        float f[8];
        const unsigned short* p0 = (const unsigned short*)&u0;
        for (int t = 0; t < 8; t++)
            f[t] = w[0] * __builtin_bit_cast(float, (unsigned int)p0[t] << 16);
        for (int c = 1; c < nch; c++) {
            const int pid = pid_of(h, i128, c);
            uint4 u = *(const uint4*)&Op[(size_t)pid * 8192 + q * 64 + d0 + jj];
            const unsigned short* p = (const unsigned short*)&u;
            for (int t = 0; t < 8; t++)
                f[t] += w[c] * __builtin_bit_cast(float, (unsigned int)p[t] << 16);
        }
        unsigned short o[8];
        for (int t = 0; t < 8; t++) o[t] = f2bf(f[t]);
        *(uint4*)&dst[jj] = *(uint4*)o;
    }
}

// ---------------------------------------------------------------- launch
extern "C" void kernel_launch(void* const* d_in, const int* in_sizes, int n_in,
                              void* d_out, int out_size, void* d_ws, size_t ws_size,
                              hipStream_t stream) {
    const float* x = (const float*)d_in[0];
    const float* wq = (const float*)d_in[1];
    const float* bq = (const float*)d_in[2];
    const float* wk = (const float*)d_in[3];
    const float* bk = (const float*)d_in[4];
    const float* wv = (const float*)d_in[5];
    const float* bv = (const float*)d_in[6];
    const float* wo = (const float*)d_in[7];
    const float* bo = (const float*)d_in[8];

    unsigned short* ws = (unsigned short*)d_ws;
    unsigned short* xb = ws;                          // 3,145,728 ush
    unsigned short* wqkvT = xb + SEQ * EMB;           // 1,769,472
    unsigned short* woT = wqkvT + 3 * EMB * EMB;      // 589,824
    unsigned short* QKb = woT + EMB * EMB;            // 4096*1536
    unsigned short* Vtb = QKb + (size_t)SEQ * 1536;   // 3,145,728
    unsigned short* ctxb = Vtb + HEADS * SEQ * HD;    // 3,145,728
    // attn-phase scratch aliases xb+wqkvT (dead after gemm_qkv):
    // Op 432*8192 = 3,538,944 ush; mArr/lArr 196,608 f32 each -> ends 4,325,376
    unsigned short* Op = xb;
    float* mArr = (float*)(ws + 3538944);
    float* lArr = mArr + 196608;

    convert_all<<<dim3(3072 + 576), 256, 0, stream>>>(x, wq, wk, wv, wo, xb, wqkvT, woT);
    gemm_qkv<<<dim3(SEQ / 64, 3 * EMB / 128), 256, 0, stream>>>(
        xb, wqkvT, bq, bk, bv, QKb, Vtb);
    attn_kernel<<<dim3(12 * 68), 256, 0, stream>>>(QKb, Vtb, ctxb, Op, mArr, lArr);
    merge_kernel<<<dim3(264), 256, 0, stream>>>(Op, mArr, lArr, ctxb);
    gemm_out<<<dim3(SEQ / 64, EMB / 64), 256, 0, stream>>>(ctxb, woT, bo, (float*)d_out);
}

// Round 10
// 180.623 us; speedup vs baseline: 1.4763x; 1.0122x over previous
//
#include <hip/hip_runtime.h>
#include <stdint.h>

#define SEQ 4096
#define EMB 768
#define HEADS 12
#define HD 64

typedef __attribute__((ext_vector_type(8))) short short8;
typedef __attribute__((ext_vector_type(4))) short short4v;
typedef __attribute__((ext_vector_type(8))) __bf16 bf16x8;
typedef __attribute__((ext_vector_type(4))) __bf16 bf16x4;
typedef __attribute__((ext_vector_type(4))) float f32x4;

// scale * log2(e) folded into Q: (1/sqrt(64)) * 1.4426950408889634
#define QSCALE 0.18033688011112043f

static __device__ __forceinline__ unsigned short f2bf(float f) {
    unsigned int u = __builtin_bit_cast(unsigned int, f);
    unsigned int r = 0x7fffu + ((u >> 16) & 1u);
    u += r;
    return (unsigned short)(u >> 16);
}

static __device__ __forceinline__ f32x4 mfma32(short8 a, short8 b, f32x4 c) {
    return __builtin_amdgcn_mfma_f32_16x16x32_bf16(
        __builtin_bit_cast(bf16x8, a), __builtin_bit_cast(bf16x8, b), c, 0, 0, 0);
}

static __device__ __forceinline__ f32x4 mfma16(short4v a, short4v b, f32x4 c) {
#if __has_builtin(__builtin_amdgcn_mfma_f32_16x16x16_bf16)
    return __builtin_amdgcn_mfma_f32_16x16x16_bf16(
        __builtin_bit_cast(bf16x4, a), __builtin_bit_cast(bf16x4, b), c, 0, 0, 0);
#else
    return __builtin_amdgcn_mfma_f32_16x16x16bf16_1k(a, b, c, 0, 0, 0);
#endif
}

static __device__ __forceinline__ short4v pack4bf(float a, float b, float c, float d) {
#if __has_builtin(__builtin_amdgcn_cvt_pk_bf16_f32)
    typedef __attribute__((ext_vector_type(2))) __bf16 bf16x2;
    bf16x2 lo = __builtin_amdgcn_cvt_pk_bf16_f32(a, b);
    bf16x2 hi = __builtin_amdgcn_cvt_pk_bf16_f32(c, d);
    uint2 u = {__builtin_bit_cast(unsigned int, lo), __builtin_bit_cast(unsigned int, hi)};
    return __builtin_bit_cast(short4v, u);
#else
    short4v p;
    p[0] = (short)f2bf(a); p[1] = (short)f2bf(b);
    p[2] = (short)f2bf(c); p[3] = (short)f2bf(d);
    return p;
#endif
}

static __device__ __forceinline__ void load_lds16(const void* g, void* l) {
    __builtin_amdgcn_global_load_lds(
        (const __attribute__((address_space(1))) unsigned int*)(uintptr_t)g,
        (__attribute__((address_space(3))) unsigned int*)(uintptr_t)l, 16, 0, 0);
}

// partial-id for (h, i128, ch>=1); 36 slots/head, 432 total
static __device__ __forceinline__ int pid_of(int h, int i128, int ch) {
    int b = (i128 < 20) ? (i128 - 10)
                        : (i128 < 30 ? 10 + (i128 - 20) * 2 : 30 + (i128 - 30) * 3);
    return h * 36 + b + (ch - 1);
}

// online-softmax step over one 64-k tile held as st[4] (S^T layout).
// Common path is LANE-LOCAL only (15-op fmax tree). Cross-quad reduce +
// rescale live inside the rare defer-max branch. m_i stays quad-uniform by
// induction, so P fed to the k-spanning PV MFMA is consistently normalized.
static __device__ __forceinline__ void softmax_q(f32x4* st, float& m_i, float& l_i,
                                                 f32x4* O, short4v* pk) {
    float t0 = fmaxf(fmaxf(st[0][0], st[0][1]), fmaxf(st[0][2], st[0][3]));
    float t1 = fmaxf(fmaxf(st[1][0], st[1][1]), fmaxf(st[1][2], st[1][3]));
    float t2 = fmaxf(fmaxf(st[2][0], st[2][1]), fmaxf(st[2][2], st[2][3]));
    float t3 = fmaxf(fmaxf(st[3][0], st[3][1]), fmaxf(st[3][2], st[3][3]));
    float mx = fmaxf(fmaxf(t0, t1), fmaxf(t2, t3));  // this lane's 16 values
    if (__ballot(mx > m_i + 5.0f)) {  // rare after warm-up
        mx = fmaxf(mx, __shfl_xor(mx, 16));
        mx = fmaxf(mx, __shfl_xor(mx, 32));  // per-q (cross-quad) max
        const bool inc = mx > m_i;
        const float mn = inc ? mx : m_i;
        const float alpha = __builtin_amdgcn_exp2f(m_i - mn);
        m_i = mn;
        l_i *= alpha;
        for (int dt = 0; dt < 4; dt++)
            for (int r = 0; r < 4; r++) O[dt][r] *= alpha;
    }
    float rs = 0.f;
    for (int nt = 0; nt < 4; nt++) {
        float p0 = __builtin_amdgcn_exp2f(st[nt][0] - m_i);
        float p1 = __builtin_amdgcn_exp2f(st[nt][1] - m_i);
        float p2 = __builtin_amdgcn_exp2f(st[nt][2] - m_i);
        float p3 = __builtin_amdgcn_exp2f(st[nt][3] - m_i);
        rs += p0 + p1 + p2 + p3;
        pk[nt] = pack4bf(p0, p1, p2, p3);
    }
    l_i += rs;  // per-lane partial; reduced across quads at epilogue
}

// ---------------------------------------------------------------- fused convert
__global__ __launch_bounds__(256) void convert_all(const float* __restrict__ x,
                                                   const float* __restrict__ wq,
                                                   const float* __restrict__ wk,
                                                   const float* __restrict__ wv,
                                                   const float* __restrict__ wo,
                                                   unsigned short* __restrict__ xb,
                                                   unsigned short* __restrict__ wqkvT,
                                                   unsigned short* __restrict__ woT) {
    __shared__ float Ls[64][65];
    const int bid = blockIdx.x;
    if (bid < 3072) {
        int i = bid * 256 + threadIdx.x;
        float4 v = ((const float4*)x)[i];
        ushort4 o = {f2bf(v.x), f2bf(v.y), f2bf(v.z), f2bf(v.w)};
        ((ushort4*)xb)[i] = o;
        return;
    }
    const int idx = bid - 3072;
    const int z = idx / 144;
    const int bx = (idx % 144) / 12, by = idx % 12;
    const float* W = (z == 0) ? wq : (z == 1) ? wk : (z == 2) ? wv : wo;
    unsigned short* dst = (z < 3) ? (wqkvT + (size_t)z * EMB * EMB) : woT;
    const int k0 = bx * 64, n0 = by * 64;
    const int r = threadIdx.x >> 2, c0 = (threadIdx.x & 3) * 16;
    for (int j = 0; j < 16; j += 4) {
        float4 v = *(const float4*)&W[(size_t)(k0 + r) * EMB + n0 + c0 + j];
        Ls[r][c0 + j] = v.x;
        Ls[r][c0 + j + 1] = v.y;
        Ls[r][c0 + j + 2] = v.z;
        Ls[r][c0 + j + 3] = v.w;
    }
    __syncthreads();
    unsigned short tmp[16];
    for (int j = 0; j < 16; j++) tmp[j] = f2bf(Ls[c0 + j][r]);
    *(uint4*)&dst[(size_t)(n0 + r) * EMB + k0 + c0] = *(uint4*)tmp;
    *(uint4*)&dst[(size_t)(n0 + r) * EMB + k0 + c0 + 8] = *(uint4*)(tmp + 8);
}

// ---------------------------------------------------------------- 64x128 QKV GEMM
__global__ __launch_bounds__(256) void gemm_qkv(const unsigned short* __restrict__ A,
                                                const unsigned short* __restrict__ Bt,
                                                const float* __restrict__ b0p,
                                                const float* __restrict__ b1p,
                                                const float* __restrict__ b2p,
                                                unsigned short* __restrict__ QKb,
                                                unsigned short* __restrict__ Vtb) {
    __shared__ __align__(16) unsigned short SMEM[12288];  // As[2]@0/2048, Bs[2]@4096/8192
    const int tid = threadIdx.x;
    const int wave = tid >> 6, lane = tid & 63, quad = lane >> 4, l16 = lane & 15;
    const int m0 = blockIdx.x * 64, n0 = blockIdx.y * 128;
    const int wm = (wave >> 1) * 32, wn = (wave & 1) * 64;
    const int lrow = lane >> 2, lcol = (lane & 3) * 8;

    f32x4 acc[2][4] = {};

    load_lds16(&A[(size_t)(m0 + wave * 16 + lrow) * EMB + lcol], &SMEM[wave * 512]);
    for (int t = 0; t < 2; t++) {
        int row = wave * 32 + t * 16 + lrow;
        load_lds16(&Bt[(size_t)(n0 + row) * EMB + lcol], &SMEM[4096 + (wave * 2 + t) * 512]);
    }
    int buf = 0;
    for (int k0 = 0; k0 < EMB; k0 += 32) {
        __syncthreads();
        if (k0 + 32 < EMB) {
            unsigned short* A_ = &SMEM[(buf ^ 1) * 2048];
            unsigned short* B_ = &SMEM[4096 + (buf ^ 1) * 4096];
            load_lds16(&A[(size_t)(m0 + wave * 16 + lrow) * EMB + k0 + 32 + lcol], &A_[wave * 512]);
            for (int t = 0; t < 2; t++) {
                int row = wave * 32 + t * 16 + lrow;
                load_lds16(&Bt[(size_t)(n0 + row) * EMB + k0 + 32 + lcol], &B_[(wave * 2 + t) * 512]);
            }
        }
        const unsigned short* A_ = &SMEM[buf * 2048];
        const unsigned short* B_ = &SMEM[4096 + buf * 4096];
        short8 a[2], b[4];
        for (int i = 0; i < 2; i++) a[i] = *(const short8*)&A_[(wm + i * 16 + l16) * 32 + quad * 8];
        for (int j = 0; j < 4; j++) b[j] = *(const short8*)&B_[(wn + j * 16 + l16) * 32 + quad * 8];
        for (int i = 0; i < 2; i++)
            for (int j = 0; j < 4; j++) acc[i][j] = mfma32(a[i], b[j], acc[i][j]);
        buf ^= 1;
    }

    const int z = n0 / EMB;  // block-uniform: 0=Q, 1=K, 2=V
    if (z < 2) {
        const float* bias = z ? b1p : b0p;
        const float sc = z ? 1.0f : QSCALE;
        for (int i = 0; i < 2; i++)
            for (int j = 0; j < 4; j++) {
                int mbase = m0 + wm + i * 16 + quad * 4;
                int n = n0 + wn + j * 16 + l16;  // 0..1535 natural col
                float bv = bias[n - z * EMB];
                for (int r = 0; r < 4; r++)
                    QKb[(size_t)(mbase + r) * 1536 + n] = f2bf((acc[i][j][r] + bv) * sc);
            }
    } else {
        // V^T epilogue for 64-row tiles (SMEM stride 72 ush ≡ 4 mod 32:
        // conflict-free as in the 128-row version's 136)
        const int nn = n0 + wn + l16 - 2 * EMB;
        for (int j = 0; j < 4; j++) {
            __syncthreads();
            const float bv = b2p[nn + j * 16];
            const int nloc = (wave & 1) * 16 + l16;
            for (int i = 0; i < 2; i++) {
                ushort4 pk;
                pk.x = f2bf(acc[i][j][0] + bv);
                pk.y = f2bf(acc[i][j][1] + bv);
                pk.z = f2bf(acc[i][j][2] + bv);
                pk.w = f2bf(acc[i][j][3] + bv);
                *(ushort4*)&SMEM[nloc * 72 + wm + i * 16 + quad * 4] = pk;
            }
            __syncthreads();
            const int nl = tid >> 3, c = tid & 7;
            const int ng = (nl >> 4) * 64 + j * 16 + (nl & 15) + n0 - 2 * EMB;
            const int hh = ng >> 6, dd = ng & 63;
            unsigned short* dst = &Vtb[(size_t)(hh * HD + dd) * SEQ + m0];
            *(uint4*)&dst[c * 8] = *(uint4*)&SMEM[nl * 72 + c * 8];
        }
    }
}

// ---------------------------------------------------------------- 64x64 out-proj GEMM
__global__ __launch_bounds__(256) void gemm_out(const unsigned short* __restrict__ A,
                                                const unsigned short* __restrict__ Bt,
                                                const float* __restrict__ bias,
                                                float* __restrict__ outp) {
    __shared__ __align__(16) unsigned short SMEM[8192];  // As[2]@0/2048, Bs[2]@4096/6144
    const int tid = threadIdx.x;
    const int wave = tid >> 6, lane = tid & 63, quad = lane >> 4, l16 = lane & 15;
    const int m0 = blockIdx.x * 64, n0 = blockIdx.y * 64;
    const int wm = (wave >> 1) * 32, wn = (wave & 1) * 32;
    const int lrow = lane >> 2, lcol = (lane & 3) * 8;

    f32x4 acc[2][2] = {};

    load_lds16(&A[(size_t)(m0 + wave * 16 + lrow) * EMB + lcol], &SMEM[wave * 512]);
    load_lds16(&Bt[(size_t)(n0 + wave * 16 + lrow) * EMB + lcol], &SMEM[4096 + wave * 512]);
    int buf = 0;
    for (int k0 = 0; k0 < EMB; k0 += 32) {
        __syncthreads();
        if (k0 + 32 < EMB) {
            unsigned short* A_ = &SMEM[(buf ^ 1) * 2048];
            unsigned short* B_ = &SMEM[4096 + (buf ^ 1) * 2048];
            load_lds16(&A[(size_t)(m0 + wave * 16 + lrow) * EMB + k0 + 32 + lcol], &A_[wave * 512]);
            load_lds16(&Bt[(size_t)(n0 + wave * 16 + lrow) * EMB + k0 + 32 + lcol], &B_[wave * 512]);
        }
        const unsigned short* A_ = &SMEM[buf * 2048];
        const unsigned short* B_ = &SMEM[4096 + buf * 2048];
        short8 a[2], b[2];
        for (int i = 0; i < 2; i++) a[i] = *(const short8*)&A_[(wm + i * 16 + l16) * 32 + quad * 8];
        for (int j = 0; j < 2; j++) b[j] = *(const short8*)&B_[(wn + j * 16 + l16) * 32 + quad * 8];
        for (int i = 0; i < 2; i++)
            for (int j = 0; j < 2; j++) acc[i][j] = mfma32(a[i], b[j], acc[i][j]);
        buf ^= 1;
    }

    for (int i = 0; i < 2; i++)
        for (int j = 0; j < 2; j++) {
            int mbase = m0 + wm + i * 16 + quad * 4;
            int n = n0 + wn + j * 16 + l16;
            float bv = bias[n];
            for (int r = 0; r < 4; r++) outp[(size_t)(mbase + r) * EMB + n] = acc[i][j][r] + bv;
        }
}

// ---------------------------------------------------------------- attention
// R20: TRIPLE-BUFFERED K/V (48 KB LDS) -> ONE barrier per 64-k tile, and
// stage->consume distance grows to a full iteration (QK(t+1) reads a buffer
// staged last iteration; PV(t) one staged two iterations ago). Iteration t:
//   barrier -> stage tile t+2 into buf[(t+2)%3] (regs in hand), issue loads
//   t+3 -> SM(t) -> QK(t+1) from buf[(t+1)%3] -> PV(t) from buf[t%3].
// Hazard: stage at iter t overwrites buf[(t-1)%3], last read by PV(t-1)
// before this iteration's barrier — safe. Rationale: R13's chain-shortening
// is the only attn lever that ever paid (-12%); R13 still has 2 barriers/tile
// with a zero-distance stage->QK visibility gap. Occupancy is LDS-flat
// (16-32 KB all ~2 blocks/CU), so 48 KB is free. Registers unchanged (~84,
// (256,3); NEVER (256,4): 64-VGPR cap -> spill, measured twice).
__global__ __launch_bounds__(256, 3) void attn_kernel(const unsigned short* __restrict__ QKb,
                                                      const unsigned short* __restrict__ Vtb,
                                                      unsigned short* __restrict__ ctxb,
                                                      unsigned short* __restrict__ Op,
                                                      float* __restrict__ mArr,
                                                      float* __restrict__ lArr) {
    __shared__ __align__(16) unsigned short Ks3[3][64 * 64];  // 24 KB
    __shared__ __align__(16) unsigned short Vs3[3][64 * 64];  // 24 KB

    const int bid = blockIdx.x;
    const int h = bid % HEADS;
    const int r2 = 67 - bid / HEADS;  // big i128 (long chunks) first
    int i128, ch, nch;
    if (r2 < 10) {
        i128 = r2; ch = 0; nch = 1;
    } else if (r2 < 30) {
        int t = r2 - 10; i128 = 10 + (t >> 1); ch = t & 1; nch = 2;
    } else if (r2 < 60) {
        int t = r2 - 30; i128 = 20 + t / 3; ch = t % 3; nch = 3;
    } else {
        int t = r2 - 60; i128 = 30 + (t >> 2); ch = t & 3; nch = 4;
    }
    const int T = 2 * i128 + 2;
    const int kb = ch * T / nch;
    const int ke = (ch + 1) * T / nch - 1;
    const int qbase = i128 * 128;
    const int tid = threadIdx.x;
    const int wave = tid >> 6, lane = tid & 63, quad = lane >> 4, l16 = lane & 15;

    const unsigned short* Qg = QKb + (size_t)h * HD;          // row stride 1536
    const unsigned short* Kg = QKb + (size_t)(EMB + h * HD);  // row stride 1536
    const unsigned short* Vh = Vtb + (size_t)h * HD * SEQ;    // [d][m]

    const int qa = qbase + wave * 32 + l16;  // set a: waves 0..3 cover 128 q-rows
    const int qb = qa + 16;                  // set b
    const short8 bQ0a = *(const short8*)&Qg[(size_t)qa * 1536 + quad * 8];
    const short8 bQ1a = *(const short8*)&Qg[(size_t)qa * 1536 + 32 + quad * 8];
    const short8 bQ0b = *(const short8*)&Qg[(size_t)qb * 1536 + quad * 8];
    const short8 bQ1b = *(const short8*)&Qg[(size_t)qb * 1536 + 32 + quad * 8];

    const int row = tid >> 2, t4 = tid & 3;  // 256 threads: 64 rows x 4 chunks
    const int swk = row & 7, swv = row & 15;

    f32x4 Oa[4] = {}, Ob[4] = {};
    float m_a = -3.0e38f, l_a = 0.f;
    float m_b = -3.0e38f, l_b = 0.f;

    uint4 kr0, kr1, vr0, vr1;

    // ---- prologue: stage tiles kb, kb+1; keep tile kb+2 in regs
    {
        const unsigned short* kp = &Kg[(size_t)(kb * 64 + row) * 1536];
        kr0 = *(const uint4*)&kp[(2 * t4) * 8];
        kr1 = *(const uint4*)&kp[(2 * t4 + 1) * 8];
        const unsigned short* vp = &Vh[(size_t)row * SEQ + kb * 64];
        vr0 = *(const uint4*)&vp[t4 * 16];
        vr1 = *(const uint4*)&vp[t4 * 16 + 8];
        unsigned short* Kd = &Ks3[kb % 3][0];
        unsigned short* Vd = &Vs3[kb % 3][0];
        *(uint4*)&Kd[row * 64 + ((2 * t4) ^ swk) * 8] = kr0;
        *(uint4*)&Kd[row * 64 + ((2 * t4 + 1) ^ swk) * 8] = kr1;
        *(uint2*)&Vd[row * 64 + ((4 * t4) ^ swv) * 4] = ((const uint2*)&vr0)[0];
        *(uint2*)&Vd[row * 64 + ((4 * t4 + 1) ^ swv) * 4] = ((const uint2*)&vr0)[1];
        *(uint2*)&Vd[row * 64 + ((4 * t4 + 2) ^ swv) * 4] = ((const uint2*)&vr1)[0];
        *(uint2*)&Vd[row * 64 + ((4 * t4 + 3) ^ swv) * 4] = ((const uint2*)&vr1)[1];
    }
    if (kb + 1 <= ke) {
        const int nb = (kb + 1) * 64;
        const unsigned short* kp = &Kg[(size_t)(nb + row) * 1536];
        kr0 = *(const uint4*)&kp[(2 * t4) * 8];
        kr1 = *(const uint4*)&kp[(2 * t4 + 1) * 8];
        const unsigned short* vp = &Vh[(size_t)row * SEQ + nb];
        vr0 = *(const uint4*)&vp[t4 * 16];
        vr1 = *(const uint4*)&vp[t4 * 16 + 8];
        unsigned short* Kd = &Ks3[(kb + 1) % 3][0];
        unsigned short* Vd = &Vs3[(kb + 1) % 3][0];
        *(uint4*)&Kd[row * 64 + ((2 * t4) ^ swk) * 8] = kr0;
        *(uint4*)&Kd[row * 64 + ((2 * t4 + 1) ^ swk) * 8] = kr1;
        *(uint2*)&Vd[row * 64 + ((4 * t4) ^ swv) * 4] = ((const uint2*)&vr0)[0];
        *(uint2*)&Vd[row * 64 + ((4 * t4 + 1) ^ swv) * 4] = ((const uint2*)&vr0)[1];
        *(uint2*)&Vd[row * 64 + ((4 * t4 + 2) ^ swv) * 4] = ((const uint2*)&vr1)[0];
        *(uint2*)&Vd[row * 64 + ((4 * t4 + 3) ^ swv) * 4] = ((const uint2*)&vr1)[1];
    }
    if (kb + 2 <= ke) {  // tile kb+2 -> regs only
        const int nb = (kb + 2) * 64;
        const unsigned short* kp = &Kg[(size_t)(nb + row) * 1536];
        kr0 = *(const uint4*)&kp[(2 * t4) * 8];
        kr1 = *(const uint4*)&kp[(2 * t4 + 1) * 8];
        const unsigned short* vp = &Vh[(size_t)row * SEQ + nb];
        vr0 = *(const uint4*)&vp[t4 * 16];
        vr1 = *(const uint4*)&vp[t4 * 16 + 8];
    }
    __syncthreads();

    const int qw = qbase + wave * 32 + 31;  // wave's last causal q-row
    const int swr = l16 & 7;

    // prime QK(kb) -> sa/sb
    f32x4 sa[4], sb[4];
    if (kb * 64 <= qw) {
        const unsigned short* Kc = &Ks3[kb % 3][0];
        for (int nt = 0; nt < 4; nt++) {
            short8 aK0 = *(const short8*)&Kc[(nt * 16 + l16) * 64 + (quad ^ swr) * 8];
            short8 aK1 = *(const short8*)&Kc[(nt * 16 + l16) * 64 + ((quad + 4) ^ swr) * 8];
            f32x4 za = {};
            za = mfma32(aK0, bQ0a, za);
            za = mfma32(aK1, bQ1a, za);
            sa[nt] = za;
            f32x4 zb = {};
            zb = mfma32(aK0, bQ0b, zb);
            zb = mfma32(aK1, bQ1b, zb);
            sb[nt] = zb;
        }
        if (kb * 64 + 63 > qbase + wave * 32) {
            for (int nt = 0; nt < 4; nt++)
                for (int r = 0; r < 4; r++) {
                    const int kk = kb * 64 + nt * 16 + quad * 4 + r;
                    if (kk > qa) sa[nt][r] = -INFINITY;
                    if (kk > qb) sb[nt][r] = -INFINITY;
                }
        }
    }

    int b0 = kb % 3;  // buffer of tile kt
    for (int kt = kb; kt <= ke; kt++) {
        const int b1 = (b0 == 2) ? 0 : b0 + 1;  // tile kt+1
        const int b2 = (b1 == 2) ? 0 : b1 + 1;  // tile kt+2

        __syncthreads();  // stage(kt+1) visible; all waves past PV(kt-1)

        if (kt + 2 <= ke) {
            // stage tile kt+2 (regs in hand) into buf b2; then issue loads kt+3
            unsigned short* Kd = &Ks3[b2][0];
            unsigned short* Vd = &Vs3[b2][0];
            *(uint4*)&Kd[row * 64 + ((2 * t4) ^ swk) * 8] = kr0;
            *(uint4*)&Kd[row * 64 + ((2 * t4 + 1) ^ swk) * 8] = kr1;
            *(uint2*)&Vd[row * 64 + ((4 * t4) ^ swv) * 4] = ((const uint2*)&vr0)[0];
            *(uint2*)&Vd[row * 64 + ((4 * t4 + 1) ^ swv) * 4] = ((const uint2*)&vr0)[1];
            *(uint2*)&Vd[row * 64 + ((4 * t4 + 2) ^ swv) * 4] = ((const uint2*)&vr1)[0];
            *(uint2*)&Vd[row * 64 + ((4 * t4 + 3) ^ swv) * 4] = ((const uint2*)&vr1)[1];
            if (kt + 3 <= ke) {
                const int nb = (kt + 3) * 64;
                const unsigned short* kp = &Kg[(size_t)(nb + row) * 1536];
                kr0 = *(const uint4*)&kp[(2 * t4) * 8];
                kr1 = *(const uint4*)&kp[(2 * t4 + 1) * 8];
                const unsigned short* vp = &Vh[(size_t)row * SEQ + nb];
                vr0 = *(const uint4*)&vp[t4 * 16];
                vr1 = *(const uint4*)&vp[t4 * 16 + 8];
            }
        }

        const int kbase = kt * 64;
        const bool cur = (kbase <= qw);

        // SM(kt): pure VALU on registers computed last iteration
        short4v pka[4], pkb[4];
        if (cur) {
            softmax_q(sa, m_a, l_a, Oa, pka);
            softmax_q(sb, m_b, l_b, Ob, pkb);
        }

        // QK(kt+1): reads buf b1, staged a FULL iteration ago (no visibility gap)
        const int kn = kbase + 64;
        if (kt < ke && kn <= qw) {
            const unsigned short* Kc = &Ks3[b1][0];
            for (int nt = 0; nt < 4; nt++) {
                short8 aK0 = *(const short8*)&Kc[(nt * 16 + l16) * 64 + (quad ^ swr) * 8];
                short8 aK1 = *(const short8*)&Kc[(nt * 16 + l16) * 64 + ((quad + 4) ^ swr) * 8];
                f32x4 za = {};
                za = mfma32(aK0, bQ0a, za);
                za = mfma32(aK1, bQ1a, za);
                sa[nt] = za;
                f32x4 zb = {};
                zb = mfma32(aK0, bQ0b, zb);
                zb = mfma32(aK1, bQ1b, zb);
                sb[nt] = zb;
            }
            if (kn + 63 > qbase + wave * 32) {
                for (int nt = 0; nt < 4; nt++)
                    for (int r = 0; r < 4; r++) {
                        const int kk = kn + nt * 16 + quad * 4 + r;
                        if (kk > qa) sa[nt][r] = -INFINITY;
                        if (kk > qb) sb[nt][r] = -INFINITY;
                    }
            }
        }

        // PV(kt): reads buf b0, staged two iterations ago
        if (cur) {
            const unsigned short* Vc = &Vs3[b0][0];
            for (int dt = 0; dt < 4; dt++)
                for (int nt = 0; nt < 4; nt++) {
                    short4v av =
                        *(const short4v*)&Vc[(dt * 16 + l16) * 64 + ((4 * nt + quad) ^ l16) * 4];
                    Oa[dt] = mfma16(av, pka[nt], Oa[dt]);
                    Ob[dt] = mfma16(av, pkb[nt], Ob[dt]);
                }
        }

        b0 = b1;
    }

    // deferred cross-lane l reduction (m is quad-uniform by construction)
    l_a += __shfl_xor(l_a, 16);
    l_a += __shfl_xor(l_a, 32);
    l_b += __shfl_xor(l_b, 16);
    l_b += __shfl_xor(l_b, 32);

    const int qla = wave * 32 + l16;  // 0..127 across 4 waves (set a)
    const int qlb = qla + 16;         // set b
    if (nch == 1) {
        const float ia = 1.f / l_a, ib = 1.f / l_b;
        for (int dt = 0; dt < 4; dt++) {
            ushort4 oa, ob;
            oa.x = f2bf(Oa[dt][0] * ia);
            oa.y = f2bf(Oa[dt][1] * ia);
            oa.z = f2bf(Oa[dt][2] * ia);
            oa.w = f2bf(Oa[dt][3] * ia);
            ob.x = f2bf(Ob[dt][0] * ib);
            ob.y = f2bf(Ob[dt][1] * ib);
            ob.z = f2bf(Ob[dt][2] * ib);
            ob.w = f2bf(Ob[dt][3] * ib);
            *(ushort4*)&ctxb[(size_t)qa * EMB + h * HD + dt * 16 + quad * 4] = oa;
            *(ushort4*)&ctxb[(size_t)qb * EMB + h * HD + dt * 16 + quad * 4] = ob;
        }
    } else {
        if (ch == 0) {
            for (int dt = 0; dt < 4; dt++) {
                ushort4 oa, ob;
                oa.x = f2bf(Oa[dt][0]);
                oa.y = f2bf(Oa[dt][1]);
                oa.z = f2bf(Oa[dt][2]);
                oa.w = f2bf(Oa[dt][3]);
                ob.x = f2bf(Ob[dt][0]);
                ob.y = f2bf(Ob[dt][1]);
                ob.z = f2bf(Ob[dt][2]);
                ob.w = f2bf(Ob[dt][3]);
                *(ushort4*)&ctxb[(size_t)qa * EMB + h * HD + dt * 16 + quad * 4] = oa;
                *(ushort4*)&ctxb[(size_t)qb * EMB + h * HD + dt * 16 + quad * 4] = ob;
            }
        } else {
            const int pid = pid_of(h, i128, ch);
            for (int dt = 0; dt < 4; dt++) {
                ushort4 oa, ob;
                oa.x = f2bf(Oa[dt][0]);
                oa.y = f2bf(Oa[dt][1]);
                oa.z = f2bf(Oa[dt][2]);
                oa.w = f2bf(Oa[dt][3]);
                ob.x = f2bf(Ob[dt][0]);
                ob.y = f2bf(Ob[dt][1]);
                ob.z = f2bf(Ob[dt][2]);
                ob.w = f2bf(Ob[dt][3]);
                *(ushort4*)&Op[(size_t)pid * 8192 + qla * 64 + dt * 16 + quad * 4] = oa;
                *(ushort4*)&Op[(size_t)pid * 8192 + qlb * 64 + dt * 16 + quad * 4] = ob;
            }
        }
        if (quad == 0) {
            const int mlb = ((h * 32 + i128) * 4 + ch) * 128;
            mArr[mlb + qla] = m_a;
            lArr[mlb + qla] = l_a;
            mArr[mlb + qlb] = m_b;
            lArr[mlb + qlb] = l_b;
        }
    }
}

// ---------------------------------------------------------------- merge (i128>=10)
__global__ __launch_bounds__(256) void merge_kernel(const unsigned short* __restrict__ Op,
                                                    const float* __restrict__ mArr,
                                                    const float* __restrict__ lArr,
                                                    unsigned short* __restrict__ ctxb) {
    const int gid = blockIdx.x;  // 0..263
    const int h = gid % HEADS;
    const int i128 = 10 + gid / HEADS;
    const int nch = (i128 < 20) ? 2 : (i128 < 30) ? 3 : 4;
    const int q = threadIdx.x >> 1, d0 = (threadIdx.x & 1) * 32;
    const int mlbase = (h * 32 + i128) * 4;

    float mc[4], lc[4];
    for (int c = 0; c < nch; c++) {
        mc[c] = mArr[(mlbase + c) * 128 + q];
        lc[c] = lArr[(mlbase + c) * 128 + q];
    }
    float M = mc[0];
    for (int c = 1; c < nch; c++) M = fmaxf(M, mc[c]);
    float w[4], L = 0.f;
    for (int c = 0; c < nch; c++) {
        w[c] = __builtin_amdgcn_exp2f(mc[c] - M);
        L += w[c] * lc[c];
    }
    const float inv = 1.f / L;
    for (int c = 0; c < nch; c++) w[c] *= inv;

    unsigned short* dst = &ctxb[(size_t)(i128 * 128 + q) * EMB + h * HD + d0];
    for (int jj = 0; jj < 32; jj += 8) {
        uint4 u0 = *(const uint4*)&dst[jj];  // chunk0 (unnormalized) in place
        float f[8];
        const unsigned short* p0 = (const unsigned short*)&u0;
        for (int t = 0; t < 8; t++)
            f[t] = w[0] * __builtin_bit_cast(float, (unsigned int)p0[t] << 16);
        for (int c = 1; c < nch; c++) {
            const int pid = pid_of(h, i128, c);
            uint4 u = *(const uint4*)&Op[(size_t)pid * 8192 + q * 64 + d0 + jj];
            const unsigned short* p = (const unsigned short*)&u;
            for (int t = 0; t < 8; t++)
                f[t] += w[c] * __builtin_bit_cast(float, (unsigned int)p[t] << 16);
        }
        unsigned short o[8];
        for (int t = 0; t < 8; t++) o[t] = f2bf(f[t]);
        *(uint4*)&dst[jj] = *(uint4*)o;
    }
}

// ---------------------------------------------------------------- launch
extern "C" void kernel_launch(void* const* d_in, const int* in_sizes, int n_in,
                              void* d_out, int out_size, void* d_ws, size_t ws_size,
                              hipStream_t stream) {
    const float* x = (const float*)d_in[0];
    const float* wq = (const float*)d_in[1];
    const float* bq = (const float*)d_in[2];
    const float* wk = (const float*)d_in[3];
    const float* bk = (const float*)d_in[4];
    const float* wv = (const float*)d_in[5];
    const float* bv = (const float*)d_in[6];
    const float* wo = (const float*)d_in[7];
    const float* bo = (const float*)d_in[8];

    unsigned short* ws = (unsigned short*)d_ws;
    unsigned short* xb = ws;                          // 3,145,728 ush
    unsigned short* wqkvT = xb + SEQ * EMB;           // 1,769,472
    unsigned short* woT = wqkvT + 3 * EMB * EMB;      // 589,824
    unsigned short* QKb = woT + EMB * EMB;            // 4096*1536
    unsigned short* Vtb = QKb + (size_t)SEQ * 1536;   // 3,145,728
    unsigned short* ctxb = Vtb + HEADS * SEQ * HD;    // 3,145,728
    // attn-phase scratch aliases xb+wqkvT (dead after gemm_qkv):
    // Op 432*8192 = 3,538,944 ush; mArr/lArr 196,608 f32 each -> ends 4,325,376
    unsigned short* Op = xb;
    float* mArr = (float*)(ws + 3538944);
    float* lArr = mArr + 196608;

    convert_all<<<dim3(3072 + 576), 256, 0, stream>>>(x, wq, wk, wv, wo, xb, wqkvT, woT);
    gemm_qkv<<<dim3(SEQ / 64, 3 * EMB / 128), 256, 0, stream>>>(
        xb, wqkvT, bq, bk, bv, QKb, Vtb);
    attn_kernel<<<dim3(12 * 68), 256, 0, stream>>>(QKb, Vtb, ctxb, Op, mArr, lArr);
    merge_kernel<<<dim3(264), 256, 0, stream>>>(Op, mArr, lArr, ctxb);
    gemm_out<<<dim3(SEQ / 64, EMB / 64), 256, 0, stream>>>(ctxb, woT, bo, (float*)d_out);
}